// Round 14
// baseline (308.287 us; speedup 1.0000x reference)
//
#include <hip/hip_runtime.h>

#define NNODES 50000
#define NEDGES 800000
#define ETOT   850000   /* NEDGES + NNODES self loops */
#define IN_CH  128
#define HID    32
#define C1     128      /* HEADS*HID */
#define NEG    0.2f
#define BNEPS  1e-5f
#define XFB2   1563     /* gemm blocks = ceil(NNODES/32) */
#define EHB    3125     /* hist blocks = NEDGES/256 */
#define WTS    160      /* WT row stride in bf16 (320B) */
#define XSS    136      /* xs LDS row stride in bf16 */
#define NB     196      /* coarse buckets = ceil(NNODES/256) */
#define THS    3136     /* TH row stride (>= EHB) */

typedef __attribute__((ext_vector_type(8))) short short8;
typedef __attribute__((ext_vector_type(4))) float f32x4;

// fp32 -> bf16 (RNE)
__device__ __forceinline__ unsigned short bf16r(float f) {
    unsigned u = __float_as_uint(f);
    return (unsigned short)((u + 0x7fffu + ((u >> 16) & 1u)) >> 16);
}
__device__ __forceinline__ unsigned bf16pair(float f0, float f1) {
    return (unsigned)bf16r(f0) | ((unsigned)bf16r(f1) << 16);
}
__device__ __forceinline__ float blo(unsigned u) { return __uint_as_float(u << 16); }
__device__ __forceinline__ float bhi(unsigned u) { return __uint_as_float(u & 0xffff0000u); }

// 256-thread block inclusive scan (4 waves, shfl_up + LDS wave offsets)
__device__ __forceinline__ int block_iscan(int v, int* ls) {
    int lane = threadIdx.x & 63, w = threadIdx.x >> 6;
    #pragma unroll
    for (int o = 1; o < 64; o <<= 1) {
        int t = __shfl_up(v, o);
        if (lane >= o) v += t;
    }
    if (lane == 63) ls[w] = v;
    __syncthreads();
    int add = 0;
    #pragma unroll
    for (int i = 0; i < 4; i++) add += (i < w) ? ls[i] : 0;
    return v + add;
}

// ---------------- prep: bf16-transposed weights + init meanbuf/pad ----------
__global__ __launch_bounds__(256) void k_prep(const float* __restrict__ Wl1,
                                              const float* __restrict__ Wr1,
                                              const float* __restrict__ Wl2,
                                              const float* __restrict__ Wr2,
                                              unsigned short* __restrict__ WT,
                                              unsigned short* __restrict__ WT2,
                                              float* __restrict__ meanbuf,
                                              unsigned* __restrict__ cpack) {
    int idx = blockIdx.x * 256 + threadIdx.x;     // 160 blocks -> 40960
    if (blockIdx.x == 0) {
        if (threadIdx.x == 0) meanbuf[0] = 0.f;
        if (threadIdx.x < 64) cpack[ETOT + threadIdx.x] = 0u;   // prefetch pad
    }
    if (idx < 32768) {
        int mat = idx >> 14, rem = idx & 16383;
        int k = rem >> 7, n = rem & 127;
        float v = mat ? Wr1[k * 128 + n] : Wl1[k * 128 + n];
        WT[(size_t)(mat * 128 + n) * WTS + k] = bf16r(v);
    } else {
        int i2 = idx - 32768;                      // 8192 elements
        int mat = i2 >> 12, rem = i2 & 4095;
        int k = rem >> 5, n = rem & 31;
        float v = mat ? Wr2[k * 32 + n] : Wl2[k * 32 + n];
        WT2[(size_t)(mat * 32 + n) * WTS + k] = bf16r(v);
    }
}

// ---------------- fused: conv1 MFMA GEMM (blocks 0..XFB2-1) -----------------
//                + LDS-histogram bucketing pass (blocks XFB2..) — NO global
//                atomics: per-block 196-bucket LDS hist -> TH[bucket][block].
__global__ __launch_bounds__(256) void k_xf_eh(
    const float* __restrict__ x,
    const float* __restrict__ bl, const float* __restrict__ br,
    const unsigned short* __restrict__ WT,
    unsigned* __restrict__ xlb, float* __restrict__ xr,
    const int* __restrict__ ei, const float* __restrict__ ea,
    int* __restrict__ TH, float* __restrict__ meanbuf) {
    __shared__ short xs_s[64 * XSS];              // rows 0-31 hi, 32-63 lo
    if (blockIdx.x >= XFB2) {
        int* ih = (int*)xs_s;                     // [0..195] bucket counters
        float* ls = (float*)(ih + 200);
        int hb = blockIdx.x - XFB2;               // hist ordinal 0..EHB-1
        int t = threadIdx.x;
        if (t < NB) ih[t] = 0;
        __syncthreads();
        int e = hb * 256 + t;                     // EHB*256 == NEDGES exactly
        float v = 0.f;
        if (e < NEDGES) {
            atomicAdd(&ih[ei[NEDGES + e] >> 8], 1);   // LDS atomic
            v = ea[e];
        }
        #pragma unroll
        for (int o = 32; o > 0; o >>= 1) v += __shfl_down(v, o, 64);
        if ((t & 63) == 0) ls[t >> 6] = v;
        __syncthreads();
        if (t < NB) TH[(size_t)t * THS + hb] = ih[t];
        if (t == 0) atomicAdd(meanbuf, ls[0] + ls[1] + ls[2] + ls[3]);
        return;
    }
    int n0g = blockIdx.x * 32;
    // ---- stage x tile: 32 nodes x 128 k, bf16 hi + lo ----
    {
        int nd = threadIdx.x >> 3, kc = (threadIdx.x & 7) * 16;
        bool valid = (n0g + nd) < NNODES;
        float xv[16];
        #pragma unroll
        for (int i = 0; i < 4; i++) {
            float4 t = valid ? ((const float4*)(x + (size_t)(n0g + nd) * IN_CH + kc))[i]
                             : make_float4(0.f, 0.f, 0.f, 0.f);
            xv[4 * i] = t.x; xv[4 * i + 1] = t.y; xv[4 * i + 2] = t.z; xv[4 * i + 3] = t.w;
        }
        unsigned hi[8], lo[8];
        #pragma unroll
        for (int i = 0; i < 8; i++) {
            unsigned short h0 = bf16r(xv[2 * i]), h1 = bf16r(xv[2 * i + 1]);
            float l0 = xv[2 * i]     - __uint_as_float(((unsigned)h0) << 16);
            float l1 = xv[2 * i + 1] - __uint_as_float(((unsigned)h1) << 16);
            hi[i] = (unsigned)h0 | ((unsigned)h1 << 16);
            lo[i] = bf16pair(l0, l1);
        }
        uint4* ph = (uint4*)&xs_s[nd * XSS + kc];
        ph[0] = make_uint4(hi[0], hi[1], hi[2], hi[3]);
        ph[1] = make_uint4(hi[4], hi[5], hi[6], hi[7]);
        uint4* pl = (uint4*)&xs_s[(nd + 32) * XSS + kc];
        pl[0] = make_uint4(lo[0], lo[1], lo[2], lo[3]);
        pl[1] = make_uint4(lo[4], lo[5], lo[6], lo[7]);
    }
    __syncthreads();
    int lane = threadIdx.x & 63;
    int lm = lane & 15, q = lane >> 4;
    int w = threadIdx.x >> 6;
    int n0 = w * 64;                               // this wave's 64 output cols
    f32x4 acc[2][4];
    #pragma unroll
    for (int mt = 0; mt < 2; mt++)
        #pragma unroll
        for (int nt = 0; nt < 4; nt++) acc[mt][nt] = (f32x4)0.f;

    #pragma unroll
    for (int ks = 0; ks < 4; ks++) {
        int k0 = ks * 32 + q * 8;
        short8 ah0 = *(const short8*)&xs_s[(lm)      * XSS + k0];
        short8 ah1 = *(const short8*)&xs_s[(16 + lm) * XSS + k0];
        short8 al0 = *(const short8*)&xs_s[(32 + lm) * XSS + k0];
        short8 al1 = *(const short8*)&xs_s[(48 + lm) * XSS + k0];
        #pragma unroll
        for (int nt = 0; nt < 4; nt++) {
            short8 bfr = *(const short8*)(WT + (size_t)(n0 + nt * 16 + lm) * WTS + k0);
            acc[0][nt] = __builtin_amdgcn_mfma_f32_16x16x32_bf16(al0, bfr, acc[0][nt], 0, 0, 0);
            acc[0][nt] = __builtin_amdgcn_mfma_f32_16x16x32_bf16(ah0, bfr, acc[0][nt], 0, 0, 0);
            acc[1][nt] = __builtin_amdgcn_mfma_f32_16x16x32_bf16(al1, bfr, acc[1][nt], 0, 0, 0);
            acc[1][nt] = __builtin_amdgcn_mfma_f32_16x16x32_bf16(ah1, bfr, acc[1][nt], 0, 0, 0);
        }
    }
    // ---- epilogue: D row=(q*4+reg), col=lm ----
    if (w < 2) {
        #pragma unroll
        for (int nt = 0; nt < 4; nt++) {
            int ch = n0 + nt * 16 + lm;
            float bv = bl[ch];
            #pragma unroll
            for (int mt = 0; mt < 2; mt++)
                #pragma unroll
                for (int r = 0; r < 4; r++) {
                    int node = n0g + mt * 16 + q * 4 + r;
                    float val = acc[mt][nt][r] + bv;
                    float pv = __shfl_xor(val, 1);
                    if ((lm & 1) == 0 && node < NNODES)
                        xlb[(size_t)node * 64 + (ch >> 1)] = bf16pair(val, pv);
                }
        }
    } else {
        #pragma unroll
        for (int nt = 0; nt < 4; nt++) {
            int ch = n0 - 128 + nt * 16 + lm;
            float bv = br[ch];
            #pragma unroll
            for (int mt = 0; mt < 2; mt++)
                #pragma unroll
                for (int r = 0; r < 4; r++) {
                    int node = n0g + mt * 16 + q * 4 + r;
                    if (node < NNODES)
                        xr[(size_t)node * C1 + ch] = acc[mt][nt][r] + bv;
                }
        }
    }
}

// ---------------- scan1: per-bucket scan of 3125 block counts (in place) ----
__global__ __launch_bounds__(256) void k_scan1(int* __restrict__ TH,
                                               int* __restrict__ btot) {
    __shared__ int ls[4];
    __shared__ int carry;
    int b = blockIdx.x, t = threadIdx.x;
    size_t base = (size_t)b * THS;
    if (t == 0) carry = 0;
    __syncthreads();
    for (int c0 = 0; c0 < 3328; c0 += 256) {
        int idx = c0 + t;
        int v = (idx < EHB) ? TH[base + idx] : 0;
        int incl = block_iscan(v, ls);
        int run = carry;
        __syncthreads();
        if (idx < EHB) TH[base + idx] = run + incl - v;
        if (t == 255) carry = run + incl;
        __syncthreads();
    }
    if (t == 0) btot[b] = carry;
}

// ---------------- scan2: bucket totals -> exclusive bucket bases ------------
__global__ __launch_bounds__(256) void k_scan2(const int* __restrict__ btot,
                                               int* __restrict__ bbe) {
    __shared__ int ls[4];
    int t = threadIdx.x;
    int v = (t < NB) ? btot[t] : 0;
    int incl = block_iscan(v, ls);
    if (t < NB) bbe[t] = incl - v;
}

// ---------------- fill2: scatter edges into bucket-sorted stream ------------
// rank within (block,bucket) via LDS atomic (consistent with pass-1 counts).
__global__ __launch_bounds__(256) void k_fill2(const int* __restrict__ ei,
                                               const float* __restrict__ ea,
                                               const int* __restrict__ TH,
                                               const int* __restrict__ bbe,
                                               uint2* __restrict__ buck) {
    __shared__ int thl[NB];
    __shared__ int rk[NB];
    int blk = blockIdx.x, t = threadIdx.x;
    if (t < NB) {
        thl[t] = bbe[t] + TH[(size_t)t * THS + blk];
        rk[t] = 0;
    }
    __syncthreads();
    int e = blk * 256 + t;                         // always < NEDGES
    int dst = ei[NEDGES + e], src = ei[e];
    int b = dst >> 8;
    int r = atomicAdd(&rk[b], 1);
    buck[thl[b] + r] = make_uint2(((unsigned)bf16r(ea[e]) << 16) | (unsigned)src,
                                  (unsigned)(dst & 255));
}

// ---------------- bsort: per-bucket node sort -> rowptr + final cpack -------
__global__ __launch_bounds__(256) void k_bsort(const uint2* __restrict__ buck,
                                               const int* __restrict__ bbe,
                                               const int* __restrict__ btot,
                                               const float* __restrict__ meanbuf,
                                               int* __restrict__ rowptr,
                                               unsigned* __restrict__ cpack) {
    __shared__ int hist[256], Pl[256], ls[4];
    int b = blockIdx.x, t = threadIdx.x;
    int n0 = b * 256;
    int ebase = bbe[b], ecnt = btot[b];
    hist[t] = 0;
    __syncthreads();
    for (int i = t; i < ecnt; i += 256) atomicAdd(&hist[buck[ebase + i].y], 1);
    __syncthreads();
    bool valid = (n0 + t) < NNODES;
    int deg = hist[t];
    int v = valid ? deg + 1 : 0;                   // +1 self loop
    int incl = block_iscan(v, ls);
    int P = incl - v;
    Pl[t] = P;
    int cb = ebase + n0;                           // edges-before + selfloops-before
    if (valid) rowptr[n0 + t] = cb + P;
    if (b == NB - 1 && t == 0) rowptr[NNODES] = ETOT;
    if (valid)                                     // self loop at slot 0
        cpack[cb + P] = ((unsigned)bf16r(meanbuf[0] * (1.0f / NEDGES)) << 16)
                        | (unsigned)(n0 + t);
    __syncthreads();
    hist[t] = 0;                                   // reuse as rank counters
    __syncthreads();
    for (int i = t; i < ecnt; i += 256) {
        uint2 ev = buck[ebase + i];
        int r = atomicAdd(&hist[ev.y], 1);
        cpack[cb + Pl[ev.y] + 1 + r] = ev.x;
    }
}

// ---------------- conv1 fused edge phase: one wave/node ---------------------
__global__ __launch_bounds__(256) void k_edge1(
    const unsigned* __restrict__ xlb, const float* __restrict__ xr,
    const int* __restrict__ rowptr, const unsigned* __restrict__ cpack,
    const float* __restrict__ We, const float* __restrict__ att,
    float* __restrict__ out1) {
    int node = blockIdx.x * 4 + (threadIdx.x >> 6);
    if (node >= NNODES) return;
    int lane = threadIdx.x & 63;
    int q = lane & 15, s = lane >> 4;
    int r0 = rowptr[node], r1 = rowptr[node + 1];
    float4 xr0 = ((const float4*)xr)[(size_t)node * 32 + 2 * q];
    float4 xr1 = ((const float4*)xr)[(size_t)node * 32 + 2 * q + 1];
    float4 we0 = ((const float4*)We)[2 * q],  we1 = ((const float4*)We)[2 * q + 1];
    float4 at0 = ((const float4*)att)[2 * q], at1 = ((const float4*)att)[2 * q + 1];
    const uint4* xlv = (const uint4*)xlb;      // row = 16 uint4 (128 ch)

    float den = 0.f;
    float a0 = 0.f, a1 = 0.f, a2 = 0.f, a3 = 0.f;
    float a4 = 0.f, a5 = 0.f, a6 = 0.f, a7 = 0.f;
    int nit = (r1 - r0 + 3) >> 2;
    int k = r0 + s;
    unsigned sc = cpack[k];                    // padded: safe
    uint4 xv = xlv[(size_t)(sc & 0xffffu) * 16 + q];
    for (int it = 0; it < nit; it++) {
        unsigned scn = cpack[k + 4];           // unconditional prefetch (padded)
        uint4 xvn = xlv[(size_t)(scn & 0xffffu) * 16 + q];
        bool ok = k < r1;
        float av = __uint_as_float(sc & 0xffff0000u);   // bf16 attr
        float x0 = blo(xv.x), x1 = bhi(xv.x), x2 = blo(xv.y), x3 = bhi(xv.y);
        float x4 = blo(xv.z), x5 = bhi(xv.z), x6 = blo(xv.w), x7 = bhi(xv.w);
        float v0 = x0 + xr0.x + av * we0.x;  v0 = v0 > 0.f ? v0 : NEG * v0;
        float v1 = x1 + xr0.y + av * we0.y;  v1 = v1 > 0.f ? v1 : NEG * v1;
        float v2 = x2 + xr0.z + av * we0.z;  v2 = v2 > 0.f ? v2 : NEG * v2;
        float v3 = x3 + xr0.w + av * we0.w;  v3 = v3 > 0.f ? v3 : NEG * v3;
        float v4 = x4 + xr1.x + av * we1.x;  v4 = v4 > 0.f ? v4 : NEG * v4;
        float v5 = x5 + xr1.y + av * we1.y;  v5 = v5 > 0.f ? v5 : NEG * v5;
        float v6 = x6 + xr1.z + av * we1.z;  v6 = v6 > 0.f ? v6 : NEG * v6;
        float v7 = x7 + xr1.w + av * we1.w;  v7 = v7 > 0.f ? v7 : NEG * v7;
        float t = v0 * at0.x + v1 * at0.y + v2 * at0.z + v3 * at0.w
                + v4 * at1.x + v5 * at1.y + v6 * at1.z + v7 * at1.w;
        t += __shfl_xor(t, 1);
        t += __shfl_xor(t, 2);                 // 4-lane group = this lane's head
        float e = ok ? __expf(t) : 0.f;
        den += e;
        a0 = fmaf(e, x0, a0); a1 = fmaf(e, x1, a1);
        a2 = fmaf(e, x2, a2); a3 = fmaf(e, x3, a3);
        a4 = fmaf(e, x4, a4); a5 = fmaf(e, x5, a5);
        a6 = fmaf(e, x6, a6); a7 = fmaf(e, x7, a7);
        k += 4; sc = scn; xv = xvn;
    }
    #pragma unroll
    for (int o = 16; o <= 32; o <<= 1) {
        den += __shfl_xor(den, o);
        a0 += __shfl_xor(a0, o); a1 += __shfl_xor(a1, o);
        a2 += __shfl_xor(a2, o); a3 += __shfl_xor(a3, o);
        a4 += __shfl_xor(a4, o); a5 += __shfl_xor(a5, o);
        a6 += __shfl_xor(a6, o); a7 += __shfl_xor(a7, o);
    }
    if (s == 0) {
        float rd = 1.f / den;
        ((float4*)out1)[(size_t)node * 32 + 2 * q] =
            make_float4(a0 * rd, a1 * rd, a2 * rd, a3 * rd);
        ((float4*)out1)[(size_t)node * 32 + 2 * q + 1] =
            make_float4(a4 * rd, a5 * rd, a6 * rd, a7 * rd);
    }
}

// ---------------- epi1 via MFMA: BN+ReLU staged, then h @ (Wl2|Wr2) ---------
__global__ __launch_bounds__(256) void k_epi(
    const float* __restrict__ out1, const float* __restrict__ bias1,
    const float* __restrict__ g1, const float* __restrict__ b1,
    const float* __restrict__ m1, const float* __restrict__ v1,
    const unsigned short* __restrict__ WT2,
    const float* __restrict__ bl2, const float* __restrict__ br2,
    unsigned* __restrict__ xlb2, float* __restrict__ xr2) {
    __shared__ short hs_s[64 * XSS];              // rows 0-31 hi, 32-63 lo
    __shared__ float A[128], B[128];
    int n0g = blockIdx.x * 32;
    if (threadIdx.x < 128) {
        int c = threadIdx.x;
        float sc = g1[c] * rsqrtf(v1[c] + BNEPS);
        A[c] = sc;
        B[c] = (bias1[c] - m1[c]) * sc + b1[c];
    }
    __syncthreads();
    {
        int nd = threadIdx.x >> 3, kc = (threadIdx.x & 7) * 16;
        bool valid = (n0g + nd) < NNODES;
        float xv[16];
        #pragma unroll
        for (int i = 0; i < 4; i++) {
            float4 t = valid ? ((const float4*)(out1 + (size_t)(n0g + nd) * C1 + kc))[i]
                             : make_float4(0.f, 0.f, 0.f, 0.f);
            xv[4 * i] = t.x; xv[4 * i + 1] = t.y; xv[4 * i + 2] = t.z; xv[4 * i + 3] = t.w;
        }
        #pragma unroll
        for (int j = 0; j < 16; j++)
            xv[j] = fmaxf(xv[j] * A[kc + j] + B[kc + j], 0.f);   // BN + ReLU
        unsigned hi[8], lo[8];
        #pragma unroll
        for (int i = 0; i < 8; i++) {
            unsigned short h0 = bf16r(xv[2 * i]), h1 = bf16r(xv[2 * i + 1]);
            float l0 = xv[2 * i]     - __uint_as_float(((unsigned)h0) << 16);
            float l1 = xv[2 * i + 1] - __uint_as_float(((unsigned)h1) << 16);
            hi[i] = (unsigned)h0 | ((unsigned)h1 << 16);
            lo[i] = bf16pair(l0, l1);
        }
        uint4* ph = (uint4*)&hs_s[nd * XSS + kc];
        ph[0] = make_uint4(hi[0], hi[1], hi[2], hi[3]);
        ph[1] = make_uint4(hi[4], hi[5], hi[6], hi[7]);
        uint4* pl = (uint4*)&hs_s[(nd + 32) * XSS + kc];
        pl[0] = make_uint4(lo[0], lo[1], lo[2], lo[3]);
        pl[1] = make_uint4(lo[4], lo[5], lo[6], lo[7]);
    }
    __syncthreads();
    int lane = threadIdx.x & 63;
    int lm = lane & 15, q = lane >> 4;
    int w = threadIdx.x >> 6;
    f32x4 acc[2];
    acc[0] = (f32x4)0.f; acc[1] = (f32x4)0.f;
    #pragma unroll
    for (int ks = 0; ks < 4; ks++) {
        int k0 = ks * 32 + q * 8;
        short8 ah0 = *(const short8*)&hs_s[(lm)      * XSS + k0];
        short8 ah1 = *(const short8*)&hs_s[(16 + lm) * XSS + k0];
        short8 al0 = *(const short8*)&hs_s[(32 + lm) * XSS + k0];
        short8 al1 = *(const short8*)&hs_s[(48 + lm) * XSS + k0];
        short8 bfr = *(const short8*)(WT2 + (size_t)(w * 16 + lm) * WTS + k0);
        acc[0] = __builtin_amdgcn_mfma_f32_16x16x32_bf16(al0, bfr, acc[0], 0, 0, 0);
        acc[0] = __builtin_amdgcn_mfma_f32_16x16x32_bf16(ah0, bfr, acc[0], 0, 0, 0);
        acc[1] = __builtin_amdgcn_mfma_f32_16x16x32_bf16(al1, bfr, acc[1], 0, 0, 0);
        acc[1] = __builtin_amdgcn_mfma_f32_16x16x32_bf16(ah1, bfr, acc[1], 0, 0, 0);
    }
    if (w < 2) {
        int ch = w * 16 + lm;                      // Wl2 col 0..31
        float bv = bl2[ch];
        #pragma unroll
        for (int mt = 0; mt < 2; mt++)
            #pragma unroll
            for (int r = 0; r < 4; r++) {
                int node = n0g + mt * 16 + q * 4 + r;
                float val = acc[mt][r] + bv;
                float pv = __shfl_xor(val, 1);
                if ((lm & 1) == 0 && node < NNODES)
                    xlb2[(size_t)node * 16 + (ch >> 1)] = bf16pair(val, pv);
            }
    } else {
        int ch = (w - 2) * 16 + lm;                // Wr2 col 0..31
        float bv = br2[ch];
        #pragma unroll
        for (int mt = 0; mt < 2; mt++)
            #pragma unroll
            for (int r = 0; r < 4; r++) {
                int node = n0g + mt * 16 + q * 4 + r;
                if (node < NNODES)
                    xr2[(size_t)node * HID + ch] = acc[mt][r] + bv;
            }
    }
}

// ---------------- conv2 fused edge phase + BN + classifier ------------------
__global__ __launch_bounds__(256) void k_edge2(
    const unsigned* __restrict__ xlb2, const float* __restrict__ xr2,
    const int* __restrict__ rowptr, const unsigned* __restrict__ cpack,
    const float* __restrict__ We2, const float* __restrict__ att2,
    const float* __restrict__ bias2,
    const float* __restrict__ g2, const float* __restrict__ b2,
    const float* __restrict__ m2, const float* __restrict__ v2,
    const float* __restrict__ W, const float* __restrict__ b,
    float* __restrict__ y) {
    int node = blockIdx.x * 4 + (threadIdx.x >> 6);
    if (node >= NNODES) return;
    int lane = threadIdx.x & 63;
    int q = lane & 3, s = lane >> 2;
    int r0 = rowptr[node], r1 = rowptr[node + 1];
    float4 xr0 = ((const float4*)xr2)[(size_t)node * 8 + 2 * q];
    float4 xr1 = ((const float4*)xr2)[(size_t)node * 8 + 2 * q + 1];
    float4 we0 = ((const float4*)We2)[2 * q],  we1 = ((const float4*)We2)[2 * q + 1];
    float4 at0 = ((const float4*)att2)[2 * q], at1 = ((const float4*)att2)[2 * q + 1];
    const uint4* xlv = (const uint4*)xlb2;     // row = 4 uint4 (32 ch)

    float den = 0.f;
    float a0 = 0.f, a1 = 0.f, a2 = 0.f, a3 = 0.f;
    float a4 = 0.f, a5 = 0.f, a6 = 0.f, a7 = 0.f;
    int nit = (r1 - r0 + 15) >> 4;
    int k = r0 + s;
    unsigned sc = cpack[k];
    uint4 xv = xlv[(size_t)(sc & 0xffffu) * 4 + q];
    for (int it = 0; it < nit; it++) {
        unsigned scn = cpack[k + 16];          // unconditional prefetch (padded)
        uint4 xvn = xlv[(size_t)(scn & 0xffffu) * 4 + q];
        bool ok = k < r1;
        float av = __uint_as_float(sc & 0xffff0000u);
        float x0 = blo(xv.x), x1 = bhi(xv.x), x2 = blo(xv.y), x3 = bhi(xv.y);
        float x4 = blo(xv.z), x5 = bhi(xv.z), x6 = blo(xv.w), x7 = bhi(xv.w);
        float v0 = x0 + xr0.x + av * we0.x;  v0 = v0 > 0.f ? v0 : NEG * v0;
        float v1 = x1 + xr0.y + av * we0.y;  v1 = v1 > 0.f ? v1 : NEG * v1;
        float v2 = x2 + xr0.z + av * we0.z;  v2 = v2 > 0.f ? v2 : NEG * v2;
        float v3 = x3 + xr0.w + av * we0.w;  v3 = v3 > 0.f ? v3 : NEG * v3;
        float v4 = x4 + xr1.x + av * we1.x;  v4 = v4 > 0.f ? v4 : NEG * v4;
        float v5 = x5 + xr1.y + av * we1.y;  v5 = v5 > 0.f ? v5 : NEG * v5;
        float v6 = x6 + xr1.z + av * we1.z;  v6 = v6 > 0.f ? v6 : NEG * v6;
        float v7 = x7 + xr1.w + av * we1.w;  v7 = v7 > 0.f ? v7 : NEG * v7;
        float t = v0 * at0.x + v1 * at0.y + v2 * at0.z + v3 * at0.w
                + v4 * at1.x + v5 * at1.y + v6 * at1.z + v7 * at1.w;
        t += __shfl_xor(t, 1);
        t += __shfl_xor(t, 2);                 // full 32-ch logit
        float e = ok ? __expf(t) : 0.f;
        den += e;
        a0 = fmaf(e, x0, a0); a1 = fmaf(e, x1, a1);
        a2 = fmaf(e, x2, a2); a3 = fmaf(e, x3, a3);
        a4 = fmaf(e, x4, a4); a5 = fmaf(e, x5, a5);
        a6 = fmaf(e, x6, a6); a7 = fmaf(e, x7, a7);
        k += 16; sc = scn; xv = xvn;
    }
    #pragma unroll
    for (int o = 4; o <= 32; o <<= 1) {
        den += __shfl_xor(den, o);
        a0 += __shfl_xor(a0, o); a1 += __shfl_xor(a1, o);
        a2 += __shfl_xor(a2, o); a3 += __shfl_xor(a3, o);
        a4 += __shfl_xor(a4, o); a5 += __shfl_xor(a5, o);
        a6 += __shfl_xor(a6, o); a7 += __shfl_xor(a7, o);
    }
    float rd = 1.f / den;
    float4 gv0 = ((const float4*)g2)[2 * q],    gv1 = ((const float4*)g2)[2 * q + 1];
    float4 bv0 = ((const float4*)b2)[2 * q],    bv1 = ((const float4*)b2)[2 * q + 1];
    float4 mv0 = ((const float4*)m2)[2 * q],    mv1 = ((const float4*)m2)[2 * q + 1];
    float4 vv0 = ((const float4*)v2)[2 * q],    vv1 = ((const float4*)v2)[2 * q + 1];
    float4 bi0 = ((const float4*)bias2)[2 * q], bi1 = ((const float4*)bias2)[2 * q + 1];
    float h0 = (a0 * rd + bi0.x - mv0.x) * (gv0.x * rsqrtf(vv0.x + BNEPS)) + bv0.x;
    float h1 = (a1 * rd + bi0.y - mv0.y) * (gv0.y * rsqrtf(vv0.y + BNEPS)) + bv0.y;
    float h2 = (a2 * rd + bi0.z - mv0.z) * (gv0.z * rsqrtf(vv0.z + BNEPS)) + bv0.z;
    float h3 = (a3 * rd + bi0.w - mv0.w) * (gv0.w * rsqrtf(vv0.w + BNEPS)) + bv0.w;
    float h4 = (a4 * rd + bi1.x - mv1.x) * (gv1.x * rsqrtf(vv1.x + BNEPS)) + bv1.x;
    float h5 = (a5 * rd + bi1.y - mv1.y) * (gv1.y * rsqrtf(vv1.y + BNEPS)) + bv1.y;
    float h6 = (a6 * rd + bi1.z - mv1.z) * (gv1.z * rsqrtf(vv1.z + BNEPS)) + bv1.z;
    float h7 = (a7 * rd + bi1.w - mv1.w) * (gv1.w * rsqrtf(vv1.w + BNEPS)) + bv1.w;
    h0 = fmaxf(h0, 0.f); h1 = fmaxf(h1, 0.f); h2 = fmaxf(h2, 0.f); h3 = fmaxf(h3, 0.f);
    h4 = fmaxf(h4, 0.f); h5 = fmaxf(h5, 0.f); h6 = fmaxf(h6, 0.f); h7 = fmaxf(h7, 0.f);
    float4 w0 = ((const float4*)W)[4 * q];
    float4 w1 = ((const float4*)W)[4 * q + 1];
    float4 w2 = ((const float4*)W)[4 * q + 2];
    float4 w3 = ((const float4*)W)[4 * q + 3];
    float t0 = h0 * w0.x + h1 * w0.z + h2 * w1.x + h3 * w1.z
             + h4 * w2.x + h5 * w2.z + h6 * w3.x + h7 * w3.z;
    float t1 = h0 * w0.y + h1 * w0.w + h2 * w1.y + h3 * w1.w
             + h4 * w2.y + h5 * w2.w + h6 * w3.y + h7 * w3.w;
    t0 += __shfl_xor(t0, 1); t0 += __shfl_xor(t0, 2);
    t1 += __shfl_xor(t1, 1); t1 += __shfl_xor(t1, 2);
    if (lane == 0) {
        y[(size_t)node * 2]     = t0 + b[0];
        y[(size_t)node * 2 + 1] = t1 + b[1];
    }
}

extern "C" void kernel_launch(void* const* d_in, const int* in_sizes, int n_in,
                              void* d_out, int out_size, void* d_ws, size_t ws_size,
                              hipStream_t stream) {
    const float* x       = (const float*)d_in[0];
    const int*   ei      = (const int*)d_in[1];
    const float* ea      = (const float*)d_in[2];
    const float* c1_Wl   = (const float*)d_in[3];
    const float* c1_bl   = (const float*)d_in[4];
    const float* c1_Wr   = (const float*)d_in[5];
    const float* c1_br   = (const float*)d_in[6];
    const float* c1_We   = (const float*)d_in[7];
    const float* c1_att  = (const float*)d_in[8];
    const float* c1_bias = (const float*)d_in[9];
    const float* bn1_g   = (const float*)d_in[10];
    const float* bn1_b   = (const float*)d_in[11];
    const float* bn1_m   = (const float*)d_in[12];
    const float* bn1_v   = (const float*)d_in[13];
    const float* c2_Wl   = (const float*)d_in[14];
    const float* c2_bl   = (const float*)d_in[15];
    const float* c2_Wr   = (const float*)d_in[16];
    const float* c2_br   = (const float*)d_in[17];
    const float* c2_We   = (const float*)d_in[18];
    const float* c2_att  = (const float*)d_in[19];
    const float* c2_bias = (const float*)d_in[20];
    const float* bn2_g   = (const float*)d_in[21];
    const float* bn2_b   = (const float*)d_in[22];
    const float* bn2_m   = (const float*)d_in[23];
    const float* bn2_v   = (const float*)d_in[24];
    const float* clf_W   = (const float*)d_in[25];
    const float* clf_b   = (const float*)d_in[26];

    float* ws = (float*)d_ws;
    size_t off = 0;
    unsigned* XLb  = (unsigned*)(ws + off); off += (size_t)NNODES * 64;  // bf16x2
    float*    XR1  = ws + off; off += (size_t)NNODES * C1;
    float*    OUT1 = ws + off; off += (size_t)NNODES * C1;
    unsigned* XLb2 = (unsigned*)(ws + off); off += (size_t)NNODES * 16;  // bf16x2
    float*    XR2  = ws + off; off += (size_t)NNODES * HID;
    unsigned* CPACK= (unsigned*)(ws + off); off += (size_t)ETOT + 64;    // 4B/edge
    unsigned short* WT  = (unsigned short*)(ws + off); off += 256 * WTS / 2;
    unsigned short* WT2 = (unsigned short*)(ws + off); off += 64 * WTS / 2;
    int*      TH   = (int*)(ws + off); off += (size_t)NB * THS;
    int*      BTOT = (int*)(ws + off); off += 256;
    int*      BBE  = (int*)(ws + off); off += 256;
    uint2*    BUCK = (uint2*)(ws + off); off += (size_t)NEDGES * 2;
    int*      ROWP = (int*)(ws + off); off += NNODES + 16;
    float*    MEANB= ws + off; off += 64;
    if (ws_size < off * sizeof(float)) return;  // workspace too small: fail loudly

    k_prep  <<<160, 256, 0, stream>>>(c1_Wl, c1_Wr, c2_Wl, c2_Wr, WT, WT2, MEANB, CPACK);
    k_xf_eh <<<XFB2 + EHB, 256, 0, stream>>>(x, c1_bl, c1_br, WT, XLb, XR1,
                                             ei, ea, TH, MEANB);
    k_scan1 <<<NB, 256, 0, stream>>>(TH, BTOT);
    k_scan2 <<<1, 256, 0, stream>>>(BTOT, BBE);
    k_fill2 <<<EHB, 256, 0, stream>>>(ei, ea, TH, BBE, BUCK);
    k_bsort <<<NB, 256, 0, stream>>>(BUCK, BBE, BTOT, MEANB, ROWP, CPACK);
    k_edge1 <<<(NNODES + 3) / 4, 256, 0, stream>>>(XLb, XR1, ROWP, CPACK, c1_We, c1_att, OUT1);
    k_epi   <<<XFB2, 256, 0, stream>>>(OUT1, c1_bias, bn1_g, bn1_b, bn1_m, bn1_v,
                                       WT2, c2_bl, c2_br, XLb2, XR2);
    k_edge2 <<<(NNODES + 3) / 4, 256, 0, stream>>>(XLb2, XR2, ROWP, CPACK, c2_We, c2_att,
                                                   c2_bias, bn2_g, bn2_b, bn2_m, bn2_v,
                                                   clf_W, clf_b, (float*)d_out);
}

// Round 15
// 303.918 us; speedup vs baseline: 1.0144x; 1.0144x over previous
//
#include <hip/hip_runtime.h>

#define NNODES 50000
#define NEDGES 800000
#define ETOT   850000   /* NEDGES + NNODES self loops */
#define IN_CH  128
#define HID    32
#define C1     128      /* HEADS*HID */
#define NEG    0.2f
#define BNEPS  1e-5f
#define XFB2   1563     /* gemm blocks = ceil(NNODES/32) */
#define EHB    3125     /* hist blocks = NEDGES/256 */
#define WTS    160      /* WT row stride in bf16 (320B) */
#define XSS    136      /* xs LDS row stride in bf16 */
#define NC     16       /* histogram replication factor */
#define SCB    196      /* scan blocks = ceil(NNODES/256) */

typedef __attribute__((ext_vector_type(8))) short short8;
typedef __attribute__((ext_vector_type(4))) float f32x4;

// fp32 -> bf16 (RNE)
__device__ __forceinline__ unsigned short bf16r(float f) {
    unsigned u = __float_as_uint(f);
    return (unsigned short)((u + 0x7fffu + ((u >> 16) & 1u)) >> 16);
}
__device__ __forceinline__ unsigned bf16pair(float f0, float f1) {
    return (unsigned)bf16r(f0) | ((unsigned)bf16r(f1) << 16);
}
__device__ __forceinline__ float blo(unsigned u) { return __uint_as_float(u << 16); }
__device__ __forceinline__ float bhi(unsigned u) { return __uint_as_float(u & 0xffff0000u); }

// 256-thread block inclusive scan (4 waves, shfl_up + LDS wave offsets)
__device__ __forceinline__ int block_iscan(int v, int* ls) {
    int lane = threadIdx.x & 63, w = threadIdx.x >> 6;
    #pragma unroll
    for (int o = 1; o < 64; o <<= 1) {
        int t = __shfl_up(v, o);
        if (lane >= o) v += t;
    }
    if (lane == 63) ls[w] = v;
    __syncthreads();
    int add = 0;
    #pragma unroll
    for (int i = 0; i < 4; i++) add += (i < w) ? ls[i] : 0;
    return v + add;
}

// ---------------- prep: bf16-transposed weights + zero HIST/MEANB -----------
__global__ __launch_bounds__(256) void k_prep(const float* __restrict__ Wl1,
                                              const float* __restrict__ Wr1,
                                              const float* __restrict__ Wl2,
                                              const float* __restrict__ Wr2,
                                              unsigned short* __restrict__ WT,
                                              unsigned short* __restrict__ WT2,
                                              int* __restrict__ hist,
                                              float* __restrict__ meanbuf) {
    int idx = blockIdx.x * 256 + threadIdx.x;     // 160 blocks -> 40960
    if (idx == 0) meanbuf[0] = 0.f;
    for (int i = idx; i < NC * NNODES; i += 160 * 256) hist[i] = 0;  // coalesced zero
    if (idx < 32768) {
        int mat = idx >> 14, rem = idx & 16383;
        int k = rem >> 7, n = rem & 127;
        float v = mat ? Wr1[k * 128 + n] : Wl1[k * 128 + n];
        WT[(size_t)(mat * 128 + n) * WTS + k] = bf16r(v);
    } else {
        int i2 = idx - 32768;                      // 8192 elements
        int mat = i2 >> 12, rem = i2 & 4095;
        int k = rem >> 5, n = rem & 31;
        float v = mat ? Wr2[k * 32 + n] : Wl2[k * 32 + n];
        WT2[(size_t)(mat * 32 + n) * WTS + k] = bf16r(v);
    }
}

// ---------------- fused & INTERLEAVED: conv1 MFMA GEMM + histogram ----------
// blockIdx%3==0 -> GEMM block (ordinal blockIdx/3); else histogram block.
// Interleaving keeps atomic-latency-bound hist blocks co-resident with
// MFMA-busy GEMM blocks on every CU for the whole kernel duration.
// Hist: atomicAdd return value saved as EOFF[e] -> k_fill needs no atomics.
__global__ __launch_bounds__(256) void k_xf_eh(
    const float* __restrict__ x,
    const float* __restrict__ bl, const float* __restrict__ br,
    const unsigned short* __restrict__ WT,
    unsigned* __restrict__ xlb, float* __restrict__ xr,
    const int* __restrict__ ei, const float* __restrict__ ea,
    int* __restrict__ hist, int* __restrict__ eoff,
    float* __restrict__ meanbuf) {
    __shared__ short xs_s[64 * XSS];              // rows 0-31 hi, 32-63 lo
    int bi = blockIdx.x;
    if (bi % 3 != 0) {
        // ---- histogram (replicated) + edge_attr mean + slot offset ----
        float* ls = (float*)xs_s;
        int hb = bi - bi / 3 - 1;                 // hist ordinal 0..3125
        if (hb >= EHB) return;
        int e = hb * 256 + threadIdx.x;
        int c = hb & (NC - 1);                    // wave-uniform copy index
        float v = 0.f;
        if (e < NEDGES) {
            eoff[e] = atomicAdd(&hist[c * NNODES + ei[NEDGES + e]], 1);
            v = ea[e];
        }
        #pragma unroll
        for (int o = 32; o > 0; o >>= 1) v += __shfl_down(v, o, 64);
        if ((threadIdx.x & 63) == 0) ls[threadIdx.x >> 6] = v;
        __syncthreads();
        if (threadIdx.x == 0) atomicAdd(meanbuf, ls[0] + ls[1] + ls[2] + ls[3]);
        return;
    }
    int n0g = (bi / 3) * 32;
    // ---- stage x tile: 32 nodes x 128 k, bf16 hi + lo ----
    {
        int nd = threadIdx.x >> 3, kc = (threadIdx.x & 7) * 16;
        bool valid = (n0g + nd) < NNODES;
        float xv[16];
        #pragma unroll
        for (int i = 0; i < 4; i++) {
            float4 t = valid ? ((const float4*)(x + (size_t)(n0g + nd) * IN_CH + kc))[i]
                             : make_float4(0.f, 0.f, 0.f, 0.f);
            xv[4 * i] = t.x; xv[4 * i + 1] = t.y; xv[4 * i + 2] = t.z; xv[4 * i + 3] = t.w;
        }
        unsigned hi[8], lo[8];
        #pragma unroll
        for (int i = 0; i < 8; i++) {
            unsigned short h0 = bf16r(xv[2 * i]), h1 = bf16r(xv[2 * i + 1]);
            float l0 = xv[2 * i]     - __uint_as_float(((unsigned)h0) << 16);
            float l1 = xv[2 * i + 1] - __uint_as_float(((unsigned)h1) << 16);
            hi[i] = (unsigned)h0 | ((unsigned)h1 << 16);
            lo[i] = bf16pair(l0, l1);
        }
        uint4* ph = (uint4*)&xs_s[nd * XSS + kc];
        ph[0] = make_uint4(hi[0], hi[1], hi[2], hi[3]);
        ph[1] = make_uint4(hi[4], hi[5], hi[6], hi[7]);
        uint4* pl = (uint4*)&xs_s[(nd + 32) * XSS + kc];
        pl[0] = make_uint4(lo[0], lo[1], lo[2], lo[3]);
        pl[1] = make_uint4(lo[4], lo[5], lo[6], lo[7]);
    }
    __syncthreads();
    int lane = threadIdx.x & 63;
    int lm = lane & 15, q = lane >> 4;
    int w = threadIdx.x >> 6;
    int n0 = w * 64;                               // this wave's 64 output cols
    f32x4 acc[2][4];
    #pragma unroll
    for (int mt = 0; mt < 2; mt++)
        #pragma unroll
        for (int nt = 0; nt < 4; nt++) acc[mt][nt] = (f32x4)0.f;

    #pragma unroll
    for (int ks = 0; ks < 4; ks++) {
        int k0 = ks * 32 + q * 8;
        short8 ah0 = *(const short8*)&xs_s[(lm)      * XSS + k0];
        short8 ah1 = *(const short8*)&xs_s[(16 + lm) * XSS + k0];
        short8 al0 = *(const short8*)&xs_s[(32 + lm) * XSS + k0];
        short8 al1 = *(const short8*)&xs_s[(48 + lm) * XSS + k0];
        #pragma unroll
        for (int nt = 0; nt < 4; nt++) {
            short8 bfr = *(const short8*)(WT + (size_t)(n0 + nt * 16 + lm) * WTS + k0);
            acc[0][nt] = __builtin_amdgcn_mfma_f32_16x16x32_bf16(al0, bfr, acc[0][nt], 0, 0, 0);
            acc[0][nt] = __builtin_amdgcn_mfma_f32_16x16x32_bf16(ah0, bfr, acc[0][nt], 0, 0, 0);
            acc[1][nt] = __builtin_amdgcn_mfma_f32_16x16x32_bf16(al1, bfr, acc[1][nt], 0, 0, 0);
            acc[1][nt] = __builtin_amdgcn_mfma_f32_16x16x32_bf16(ah1, bfr, acc[1][nt], 0, 0, 0);
        }
    }
    // ---- epilogue: D row=(q*4+reg), col=lm ----
    if (w < 2) {
        #pragma unroll
        for (int nt = 0; nt < 4; nt++) {
            int ch = n0 + nt * 16 + lm;
            float bv = bl[ch];
            #pragma unroll
            for (int mt = 0; mt < 2; mt++)
                #pragma unroll
                for (int r = 0; r < 4; r++) {
                    int node = n0g + mt * 16 + q * 4 + r;
                    float val = acc[mt][nt][r] + bv;
                    float pv = __shfl_xor(val, 1);
                    if ((lm & 1) == 0 && node < NNODES)
                        xlb[(size_t)node * 64 + (ch >> 1)] = bf16pair(val, pv);
                }
        }
    } else {
        #pragma unroll
        for (int nt = 0; nt < 4; nt++) {
            int ch = n0 - 128 + nt * 16 + lm;
            float bv = br[ch];
            #pragma unroll
            for (int mt = 0; mt < 2; mt++)
                #pragma unroll
                for (int r = 0; r < 4; r++) {
                    int node = n0g + mt * 16 + q * 4 + r;
                    if (node < NNODES)
                        xr[(size_t)node * C1 + ch] = acc[mt][nt][r] + bv;
                }
        }
    }
}

// ---------------- reduce 16 histogram copies -> DEG + per-block sums --------
// hist[c][d] becomes exclusive prefix over c (slot base within node d's list)
__global__ __launch_bounds__(256) void k_red(int* __restrict__ hist,
                                             int* __restrict__ deg,
                                             int* __restrict__ bsum) {
    __shared__ int ls[4];
    int d = blockIdx.x * 256 + threadIdx.x;
    int s = 0;
    if (d < NNODES) {
        #pragma unroll
        for (int c = 0; c < NC; c++) {
            int v = hist[c * NNODES + d];
            hist[c * NNODES + d] = s;
            s += v;
        }
        deg[d] = s;
    }
    int v = (d < NNODES) ? s + 1 : 0;              // +1 = self loop
    #pragma unroll
    for (int o = 32; o > 0; o >>= 1) v += __shfl_down(v, o, 64);
    if ((threadIdx.x & 63) == 0) ls[threadIdx.x >> 6] = v;
    __syncthreads();
    if (threadIdx.x == 0) bsum[blockIdx.x] = ls[0] + ls[1] + ls[2] + ls[3];
}

// ---------------- scan the SCB block sums -> exclusive block offsets --------
__global__ __launch_bounds__(256) void k_bscan(const int* __restrict__ bsum,
                                               int* __restrict__ boff) {
    __shared__ int ls[4];
    int t = threadIdx.x;
    int v = (t < SCB) ? bsum[t] : 0;
    int incl = block_iscan(v, ls);
    if (t < SCB) boff[t] = incl - v;
}

// ---------------- rowptr: block offset + in-block exclusive scan ------------
__global__ __launch_bounds__(256) void k_rowp(const int* __restrict__ deg,
                                              const int* __restrict__ boff,
                                              int* __restrict__ rowptr) {
    __shared__ int ls[4];
    int d = blockIdx.x * 256 + threadIdx.x;
    int v = (d < NNODES) ? deg[d] + 1 : 0;
    int incl = block_iscan(v, ls);
    int base = boff[blockIdx.x];
    if (d < NNODES) rowptr[d] = base + incl - v;
    if (d == NNODES - 1) rowptr[NNODES] = base + incl;
}

// ---------------- CSR fill: ATOMIC-FREE. pos = rowptr + prefix + eoff -------
__global__ __launch_bounds__(256) void k_fill(const int* __restrict__ ei,
                                              const float* __restrict__ ea,
                                              const int* __restrict__ rowptr,
                                              const float* __restrict__ meanbuf,
                                              const int* __restrict__ hist,
                                              const int* __restrict__ eoff,
                                              unsigned* __restrict__ cpack) {
    int e = blockIdx.x * 256 + threadIdx.x;
    if (e < NEDGES) {
        int d = ei[NEDGES + e];
        int c = (e >> 8) & (NC - 1);
        int pos = rowptr[d] + 1 + hist[c * NNODES + d] + eoff[e];
        cpack[pos] = ((unsigned)bf16r(ea[e]) << 16) | (unsigned)ei[e];
    } else if (e < NEDGES + NNODES) {
        int i = e - NEDGES;
        cpack[rowptr[i]] = ((unsigned)bf16r(meanbuf[0] * (1.0f / NEDGES)) << 16) | (unsigned)i;
    } else if (e < NEDGES + NNODES + 64) {
        cpack[ETOT + e - NEDGES - NNODES] = 0u;
    }
}

// ---------------- conv1 fused edge phase: one wave/node ---------------------
// lane: q=lane&15 owns channels {8q..8q+7} (one uint4 bf16 gather); slot
// s=lane>>4 -> 4 edges in flight. Head logit = 4-lane xor reduce.
__global__ __launch_bounds__(256) void k_edge1(
    const unsigned* __restrict__ xlb, const float* __restrict__ xr,
    const int* __restrict__ rowptr, const unsigned* __restrict__ cpack,
    const float* __restrict__ We, const float* __restrict__ att,
    float* __restrict__ out1) {
    int node = blockIdx.x * 4 + (threadIdx.x >> 6);
    if (node >= NNODES) return;
    int lane = threadIdx.x & 63;
    int q = lane & 15, s = lane >> 4;
    int r0 = rowptr[node], r1 = rowptr[node + 1];
    float4 xr0 = ((const float4*)xr)[(size_t)node * 32 + 2 * q];
    float4 xr1 = ((const float4*)xr)[(size_t)node * 32 + 2 * q + 1];
    float4 we0 = ((const float4*)We)[2 * q],  we1 = ((const float4*)We)[2 * q + 1];
    float4 at0 = ((const float4*)att)[2 * q], at1 = ((const float4*)att)[2 * q + 1];
    const uint4* xlv = (const uint4*)xlb;      // row = 16 uint4 (128 ch)

    float den = 0.f;
    float a0 = 0.f, a1 = 0.f, a2 = 0.f, a3 = 0.f;
    float a4 = 0.f, a5 = 0.f, a6 = 0.f, a7 = 0.f;
    int nit = (r1 - r0 + 3) >> 2;
    int k = r0 + s;
    unsigned sc = cpack[k];                    // padded: safe
    uint4 xv = xlv[(size_t)(sc & 0xffffu) * 16 + q];
    for (int it = 0; it < nit; it++) {
        unsigned scn = cpack[k + 4];           // unconditional prefetch (padded)
        uint4 xvn = xlv[(size_t)(scn & 0xffffu) * 16 + q];
        bool ok = k < r1;
        float av = __uint_as_float(sc & 0xffff0000u);   // bf16 attr
        float x0 = blo(xv.x), x1 = bhi(xv.x), x2 = blo(xv.y), x3 = bhi(xv.y);
        float x4 = blo(xv.z), x5 = bhi(xv.z), x6 = blo(xv.w), x7 = bhi(xv.w);
        float v0 = x0 + xr0.x + av * we0.x;  v0 = v0 > 0.f ? v0 : NEG * v0;
        float v1 = x1 + xr0.y + av * we0.y;  v1 = v1 > 0.f ? v1 : NEG * v1;
        float v2 = x2 + xr0.z + av * we0.z;  v2 = v2 > 0.f ? v2 : NEG * v2;
        float v3 = x3 + xr0.w + av * we0.w;  v3 = v3 > 0.f ? v3 : NEG * v3;
        float v4 = x4 + xr1.x + av * we1.x;  v4 = v4 > 0.f ? v4 : NEG * v4;
        float v5 = x5 + xr1.y + av * we1.y;  v5 = v5 > 0.f ? v5 : NEG * v5;
        float v6 = x6 + xr1.z + av * we1.z;  v6 = v6 > 0.f ? v6 : NEG * v6;
        float v7 = x7 + xr1.w + av * we1.w;  v7 = v7 > 0.f ? v7 : NEG * v7;
        float t = v0 * at0.x + v1 * at0.y + v2 * at0.z + v3 * at0.w
                + v4 * at1.x + v5 * at1.y + v6 * at1.z + v7 * at1.w;
        t += __shfl_xor(t, 1);
        t += __shfl_xor(t, 2);                 // 4-lane group = this lane's head
        float e = ok ? __expf(t) : 0.f;
        den += e;
        a0 = fmaf(e, x0, a0); a1 = fmaf(e, x1, a1);
        a2 = fmaf(e, x2, a2); a3 = fmaf(e, x3, a3);
        a4 = fmaf(e, x4, a4); a5 = fmaf(e, x5, a5);
        a6 = fmaf(e, x6, a6); a7 = fmaf(e, x7, a7);
        k += 4; sc = scn; xv = xvn;
    }
    // merge the 4 slots (lanes q, q+16, q+32, q+48 hold same channels/head)
    #pragma unroll
    for (int o = 16; o <= 32; o <<= 1) {
        den += __shfl_xor(den, o);
        a0 += __shfl_xor(a0, o); a1 += __shfl_xor(a1, o);
        a2 += __shfl_xor(a2, o); a3 += __shfl_xor(a3, o);
        a4 += __shfl_xor(a4, o); a5 += __shfl_xor(a5, o);
        a6 += __shfl_xor(a6, o); a7 += __shfl_xor(a7, o);
    }
    if (s == 0) {
        float rd = 1.f / den;
        ((float4*)out1)[(size_t)node * 32 + 2 * q] =
            make_float4(a0 * rd, a1 * rd, a2 * rd, a3 * rd);
        ((float4*)out1)[(size_t)node * 32 + 2 * q + 1] =
            make_float4(a4 * rd, a5 * rd, a6 * rd, a7 * rd);
    }
}

// ---------------- epi1 via MFMA: BN+ReLU staged, then h @ (Wl2|Wr2) ---------
__global__ __launch_bounds__(256) void k_epi(
    const float* __restrict__ out1, const float* __restrict__ bias1,
    const float* __restrict__ g1, const float* __restrict__ b1,
    const float* __restrict__ m1, const float* __restrict__ v1,
    const unsigned short* __restrict__ WT2,
    const float* __restrict__ bl2, const float* __restrict__ br2,
    unsigned* __restrict__ xlb2, float* __restrict__ xr2) {
    __shared__ short hs_s[64 * XSS];              // rows 0-31 hi, 32-63 lo
    __shared__ float A[128], B[128];
    int n0g = blockIdx.x * 32;
    if (threadIdx.x < 128) {
        int c = threadIdx.x;
        float sc = g1[c] * rsqrtf(v1[c] + BNEPS);
        A[c] = sc;
        B[c] = (bias1[c] - m1[c]) * sc + b1[c];
    }
    __syncthreads();
    {
        int nd = threadIdx.x >> 3, kc = (threadIdx.x & 7) * 16;
        bool valid = (n0g + nd) < NNODES;
        float xv[16];
        #pragma unroll
        for (int i = 0; i < 4; i++) {
            float4 t = valid ? ((const float4*)(out1 + (size_t)(n0g + nd) * C1 + kc))[i]
                             : make_float4(0.f, 0.f, 0.f, 0.f);
            xv[4 * i] = t.x; xv[4 * i + 1] = t.y; xv[4 * i + 2] = t.z; xv[4 * i + 3] = t.w;
        }
        #pragma unroll
        for (int j = 0; j < 16; j++)
            xv[j] = fmaxf(xv[j] * A[kc + j] + B[kc + j], 0.f);   // BN + ReLU
        unsigned hi[8], lo[8];
        #pragma unroll
        for (int i = 0; i < 8; i++) {
            unsigned short h0 = bf16r(xv[2 * i]), h1 = bf16r(xv[2 * i + 1]);
            float l0 = xv[2 * i]     - __uint_as_float(((unsigned)h0) << 16);
            float l1 = xv[2 * i + 1] - __uint_as_float(((unsigned)h1) << 16);
            hi[i] = (unsigned)h0 | ((unsigned)h1 << 16);
            lo[i] = bf16pair(l0, l1);
        }
        uint4* ph = (uint4*)&hs_s[nd * XSS + kc];
        ph[0] = make_uint4(hi[0], hi[1], hi[2], hi[3]);
        ph[1] = make_uint4(hi[4], hi[5], hi[6], hi[7]);
        uint4* pl = (uint4*)&hs_s[(nd + 32) * XSS + kc];
        pl[0] = make_uint4(lo[0], lo[1], lo[2], lo[3]);
        pl[1] = make_uint4(lo[4], lo[5], lo[6], lo[7]);
    }
    __syncthreads();
    int lane = threadIdx.x & 63;
    int lm = lane & 15, q = lane >> 4;
    int w = threadIdx.x >> 6;
    f32x4 acc[2];
    acc[0] = (f32x4)0.f; acc[1] = (f32x4)0.f;
    #pragma unroll
    for (int ks = 0; ks < 4; ks++) {
        int k0 = ks * 32 + q * 8;
        short8 ah0 = *(const short8*)&hs_s[(lm)      * XSS + k0];
        short8 ah1 = *(const short8*)&hs_s[(16 + lm) * XSS + k0];
        short8 al0 = *(const short8*)&hs_s[(32 + lm) * XSS + k0];
        short8 al1 = *(const short8*)&hs_s[(48 + lm) * XSS + k0];
        short8 bfr = *(const short8*)(WT2 + (size_t)(w * 16 + lm) * WTS + k0);
        acc[0] = __builtin_amdgcn_mfma_f32_16x16x32_bf16(al0, bfr, acc[0], 0, 0, 0);
        acc[0] = __builtin_amdgcn_mfma_f32_16x16x32_bf16(ah0, bfr, acc[0], 0, 0, 0);
        acc[1] = __builtin_amdgcn_mfma_f32_16x16x32_bf16(al1, bfr, acc[1], 0, 0, 0);
        acc[1] = __builtin_amdgcn_mfma_f32_16x16x32_bf16(ah1, bfr, acc[1], 0, 0, 0);
    }
    if (w < 2) {
        int ch = w * 16 + lm;                      // Wl2 col 0..31
        float bv = bl2[ch];
        #pragma unroll
        for (int mt = 0; mt < 2; mt++)
            #pragma unroll
            for (int r = 0; r < 4; r++) {
                int node = n0g + mt * 16 + q * 4 + r;
                float val = acc[mt][r] + bv;
                float pv = __shfl_xor(val, 1);
                if ((lm & 1) == 0 && node < NNODES)
                    xlb2[(size_t)node * 16 + (ch >> 1)] = bf16pair(val, pv);
            }
    } else {
        int ch = (w - 2) * 16 + lm;                // Wr2 col 0..31
        float bv = br2[ch];
        #pragma unroll
        for (int mt = 0; mt < 2; mt++)
            #pragma unroll
            for (int r = 0; r < 4; r++) {
                int node = n0g + mt * 16 + q * 4 + r;
                if (node < NNODES)
                    xr2[(size_t)node * HID + ch] = acc[mt][r] + bv;
            }
    }
}

// ---------------- conv2 fused edge phase + BN + classifier ------------------
// lane: q=lane&3 owns channels {8q..8q+7}; slot s=lane>>2 -> 16 edges in flight
__global__ __launch_bounds__(256) void k_edge2(
    const unsigned* __restrict__ xlb2, const float* __restrict__ xr2,
    const int* __restrict__ rowptr, const unsigned* __restrict__ cpack,
    const float* __restrict__ We2, const float* __restrict__ att2,
    const float* __restrict__ bias2,
    const float* __restrict__ g2, const float* __restrict__ b2,
    const float* __restrict__ m2, const float* __restrict__ v2,
    const float* __restrict__ W, const float* __restrict__ b,
    float* __restrict__ y) {
    int node = blockIdx.x * 4 + (threadIdx.x >> 6);
    if (node >= NNODES) return;
    int lane = threadIdx.x & 63;
    int q = lane & 3, s = lane >> 2;
    int r0 = rowptr[node], r1 = rowptr[node + 1];
    float4 xr0 = ((const float4*)xr2)[(size_t)node * 8 + 2 * q];
    float4 xr1 = ((const float4*)xr2)[(size_t)node * 8 + 2 * q + 1];
    float4 we0 = ((const float4*)We2)[2 * q],  we1 = ((const float4*)We2)[2 * q + 1];
    float4 at0 = ((const float4*)att2)[2 * q], at1 = ((const float4*)att2)[2 * q + 1];
    const uint4* xlv = (const uint4*)xlb2;     // row = 4 uint4 (32 ch)

    float den = 0.f;
    float a0 = 0.f, a1 = 0.f, a2 = 0.f, a3 = 0.f;
    float a4 = 0.f, a5 = 0.f, a6 = 0.f, a7 = 0.f;
    int nit = (r1 - r0 + 15) >> 4;
    int k = r0 + s;
    unsigned sc = cpack[k];
    uint4 xv = xlv[(size_t)(sc & 0xffffu) * 4 + q];
    for (int it = 0; it < nit; it++) {
        unsigned scn = cpack[k + 16];          // unconditional prefetch (padded)
        uint4 xvn = xlv[(size_t)(scn & 0xffffu) * 4 + q];
        bool ok = k < r1;
        float av = __uint_as_float(sc & 0xffff0000u);
        float x0 = blo(xv.x), x1 = bhi(xv.x), x2 = blo(xv.y), x3 = bhi(xv.y);
        float x4 = blo(xv.z), x5 = bhi(xv.z), x6 = blo(xv.w), x7 = bhi(xv.w);
        float v0 = x0 + xr0.x + av * we0.x;  v0 = v0 > 0.f ? v0 : NEG * v0;
        float v1 = x1 + xr0.y + av * we0.y;  v1 = v1 > 0.f ? v1 : NEG * v1;
        float v2 = x2 + xr0.z + av * we0.z;  v2 = v2 > 0.f ? v2 : NEG * v2;
        float v3 = x3 + xr0.w + av * we0.w;  v3 = v3 > 0.f ? v3 : NEG * v3;
        float v4 = x4 + xr1.x + av * we1.x;  v4 = v4 > 0.f ? v4 : NEG * v4;
        float v5 = x5 + xr1.y + av * we1.y;  v5 = v5 > 0.f ? v5 : NEG * v5;
        float v6 = x6 + xr1.z + av * we1.z;  v6 = v6 > 0.f ? v6 : NEG * v6;
        float v7 = x7 + xr1.w + av * we1.w;  v7 = v7 > 0.f ? v7 : NEG * v7;
        float t = v0 * at0.x + v1 * at0.y + v2 * at0.z + v3 * at0.w
                + v4 * at1.x + v5 * at1.y + v6 * at1.z + v7 * at1.w;
        t += __shfl_xor(t, 1);
        t += __shfl_xor(t, 2);                 // full 32-ch logit
        float e = ok ? __expf(t) : 0.f;
        den += e;
        a0 = fmaf(e, x0, a0); a1 = fmaf(e, x1, a1);
        a2 = fmaf(e, x2, a2); a3 = fmaf(e, x3, a3);
        a4 = fmaf(e, x4, a4); a5 = fmaf(e, x5, a5);
        a6 = fmaf(e, x6, a6); a7 = fmaf(e, x7, a7);
        k += 16; sc = scn; xv = xvn;
    }
    #pragma unroll
    for (int o = 4; o <= 32; o <<= 1) {
        den += __shfl_xor(den, o);
        a0 += __shfl_xor(a0, o); a1 += __shfl_xor(a1, o);
        a2 += __shfl_xor(a2, o); a3 += __shfl_xor(a3, o);
        a4 += __shfl_xor(a4, o); a5 += __shfl_xor(a5, o);
        a6 += __shfl_xor(a6, o); a7 += __shfl_xor(a7, o);
    }
    float rd = 1.f / den;
    float4 gv0 = ((const float4*)g2)[2 * q],    gv1 = ((const float4*)g2)[2 * q + 1];
    float4 bv0 = ((const float4*)b2)[2 * q],    bv1 = ((const float4*)b2)[2 * q + 1];
    float4 mv0 = ((const float4*)m2)[2 * q],    mv1 = ((const float4*)m2)[2 * q + 1];
    float4 vv0 = ((const float4*)v2)[2 * q],    vv1 = ((const float4*)v2)[2 * q + 1];
    float4 bi0 = ((const float4*)bias2)[2 * q], bi1 = ((const float4*)bias2)[2 * q + 1];
    float h0 = (a0 * rd + bi0.x - mv0.x) * (gv0.x * rsqrtf(vv0.x + BNEPS)) + bv0.x;
    float h1 = (a1 * rd + bi0.y - mv0.y) * (gv0.y * rsqrtf(vv0.y + BNEPS)) + bv0.y;
    float h2 = (a2 * rd + bi0.z - mv0.z) * (gv0.z * rsqrtf(vv0.z + BNEPS)) + bv0.z;
    float h3 = (a3 * rd + bi0.w - mv0.w) * (gv0.w * rsqrtf(vv0.w + BNEPS)) + bv0.w;
    float h4 = (a4 * rd + bi1.x - mv1.x) * (gv1.x * rsqrtf(vv1.x + BNEPS)) + bv1.x;
    float h5 = (a5 * rd + bi1.y - mv1.y) * (gv1.y * rsqrtf(vv1.y + BNEPS)) + bv1.y;
    float h6 = (a6 * rd + bi1.z - mv1.z) * (gv1.z * rsqrtf(vv1.z + BNEPS)) + bv1.z;
    float h7 = (a7 * rd + bi1.w - mv1.w) * (gv1.w * rsqrtf(vv1.w + BNEPS)) + bv1.w;
    h0 = fmaxf(h0, 0.f); h1 = fmaxf(h1, 0.f); h2 = fmaxf(h2, 0.f); h3 = fmaxf(h3, 0.f);
    h4 = fmaxf(h4, 0.f); h5 = fmaxf(h5, 0.f); h6 = fmaxf(h6, 0.f); h7 = fmaxf(h7, 0.f);
    float4 w0 = ((const float4*)W)[4 * q];
    float4 w1 = ((const float4*)W)[4 * q + 1];
    float4 w2 = ((const float4*)W)[4 * q + 2];
    float4 w3 = ((const float4*)W)[4 * q + 3];
    float t0 = h0 * w0.x + h1 * w0.z + h2 * w1.x + h3 * w1.z
             + h4 * w2.x + h5 * w2.z + h6 * w3.x + h7 * w3.z;
    float t1 = h0 * w0.y + h1 * w0.w + h2 * w1.y + h3 * w1.w
             + h4 * w2.y + h5 * w2.w + h6 * w3.y + h7 * w3.w;
    t0 += __shfl_xor(t0, 1); t0 += __shfl_xor(t0, 2);
    t1 += __shfl_xor(t1, 1); t1 += __shfl_xor(t1, 2);
    if (lane == 0) {
        y[(size_t)node * 2]     = t0 + b[0];
        y[(size_t)node * 2 + 1] = t1 + b[1];
    }
}

extern "C" void kernel_launch(void* const* d_in, const int* in_sizes, int n_in,
                              void* d_out, int out_size, void* d_ws, size_t ws_size,
                              hipStream_t stream) {
    const float* x       = (const float*)d_in[0];
    const int*   ei      = (const int*)d_in[1];
    const float* ea      = (const float*)d_in[2];
    const float* c1_Wl   = (const float*)d_in[3];
    const float* c1_bl   = (const float*)d_in[4];
    const float* c1_Wr   = (const float*)d_in[5];
    const float* c1_br   = (const float*)d_in[6];
    const float* c1_We   = (const float*)d_in[7];
    const float* c1_att  = (const float*)d_in[8];
    const float* c1_bias = (const float*)d_in[9];
    const float* bn1_g   = (const float*)d_in[10];
    const float* bn1_b   = (const float*)d_in[11];
    const float* bn1_m   = (const float*)d_in[12];
    const float* bn1_v   = (const float*)d_in[13];
    const float* c2_Wl   = (const float*)d_in[14];
    const float* c2_bl   = (const float*)d_in[15];
    const float* c2_Wr   = (const float*)d_in[16];
    const float* c2_br   = (const float*)d_in[17];
    const float* c2_We   = (const float*)d_in[18];
    const float* c2_att  = (const float*)d_in[19];
    const float* c2_bias = (const float*)d_in[20];
    const float* bn2_g   = (const float*)d_in[21];
    const float* bn2_b   = (const float*)d_in[22];
    const float* bn2_m   = (const float*)d_in[23];
    const float* bn2_v   = (const float*)d_in[24];
    const float* clf_W   = (const float*)d_in[25];
    const float* clf_b   = (const float*)d_in[26];

    float* ws = (float*)d_ws;
    size_t off = 0;
    unsigned* XLb  = (unsigned*)(ws + off); off += (size_t)NNODES * 64;  // bf16x2
    float*    XR1  = ws + off; off += (size_t)NNODES * C1;
    float*    OUT1 = ws + off; off += (size_t)NNODES * C1;
    unsigned* XLb2 = (unsigned*)(ws + off); off += (size_t)NNODES * 16;  // bf16x2
    float*    XR2  = ws + off; off += (size_t)NNODES * HID;
    unsigned* CPACK= (unsigned*)(ws + off); off += (size_t)ETOT + 64;    // 4B/edge
    unsigned short* WT  = (unsigned short*)(ws + off); off += 256 * WTS / 2;
    unsigned short* WT2 = (unsigned short*)(ws + off); off += 64 * WTS / 2;
    int*      EOFF = (int*)(ws + off); off += NEDGES;
    int*      ROWP = (int*)(ws + off); off += NNODES + 16;
    int*      DEG  = (int*)(ws + off); off += NNODES;
    int*      BSUM = (int*)(ws + off); off += 256;
    int*      BOFF = (int*)(ws + off); off += 256;
    int*      HIST = (int*)(ws + off); off += (size_t)NC * NNODES;  // zeroed by k_prep
    float*    MEANB= ws + off; off += 64;
    if (ws_size < off * sizeof(float)) return;  // workspace too small: fail loudly

    k_prep  <<<160, 256, 0, stream>>>(c1_Wl, c1_Wr, c2_Wl, c2_Wr, WT, WT2, HIST, MEANB);
    k_xf_eh <<<3 * XFB2, 256, 0, stream>>>(x, c1_bl, c1_br, WT, XLb, XR1,
                                           ei, ea, HIST, EOFF, MEANB);
    k_red   <<<SCB, 256, 0, stream>>>(HIST, DEG, BSUM);
    k_bscan <<<1, 256, 0, stream>>>(BSUM, BOFF);
    k_rowp  <<<SCB, 256, 0, stream>>>(DEG, BOFF, ROWP);
    k_fill  <<<(NEDGES + NNODES + 64 + 255) / 256, 256, 0, stream>>>(ei, ea, ROWP, MEANB, HIST, EOFF, CPACK);
    k_edge1 <<<(NNODES + 3) / 4, 256, 0, stream>>>(XLb, XR1, ROWP, CPACK, c1_We, c1_att, OUT1);
    k_epi   <<<XFB2, 256, 0, stream>>>(OUT1, c1_bias, bn1_g, bn1_b, bn1_m, bn1_v,
                                       WT2, c2_bl, c2_br, XLb2, XR2);
    k_edge2 <<<(NNODES + 3) / 4, 256, 0, stream>>>(XLb2, XR2, ROWP, CPACK, c2_We, c2_att,
                                                   c2_bias, bn2_g, bn2_b, bn2_m, bn2_v,
                                                   clf_W, clf_b, (float*)d_out);
}

// Round 16
// 300.106 us; speedup vs baseline: 1.0273x; 1.0127x over previous
//
#include <hip/hip_runtime.h>

#define NNODES 50000
#define NEDGES 800000
#define ETOT   850000   /* NEDGES + NNODES self loops */
#define IN_CH  128
#define HID    32
#define C1     128      /* HEADS*HID */
#define NEG    0.2f
#define BNEPS  1e-5f
#define XFB2   1563     /* gemm blocks = ceil(NNODES/32) */
#define EHB    3125     /* hist blocks = NEDGES/256 */
#define WTS    160      /* WT row stride in bf16 (320B) */
#define XSS    136      /* xs LDS row stride in bf16 */
#define NC     16       /* histogram replication factor */
#define SCB    196      /* scan blocks = ceil(NNODES/256) */

typedef __attribute__((ext_vector_type(8))) short short8;
typedef __attribute__((ext_vector_type(4))) float f32x4;

// fp32 -> bf16 (RNE)
__device__ __forceinline__ unsigned short bf16r(float f) {
    unsigned u = __float_as_uint(f);
    return (unsigned short)((u + 0x7fffu + ((u >> 16) & 1u)) >> 16);
}
__device__ __forceinline__ unsigned bf16pair(float f0, float f1) {
    return (unsigned)bf16r(f0) | ((unsigned)bf16r(f1) << 16);
}
__device__ __forceinline__ float blo(unsigned u) { return __uint_as_float(u << 16); }
__device__ __forceinline__ float bhi(unsigned u) { return __uint_as_float(u & 0xffff0000u); }

// 256-thread block inclusive scan (4 waves, shfl_up + LDS wave offsets)
__device__ __forceinline__ int block_iscan(int v, int* ls) {
    int lane = threadIdx.x & 63, w = threadIdx.x >> 6;
    #pragma unroll
    for (int o = 1; o < 64; o <<= 1) {
        int t = __shfl_up(v, o);
        if (lane >= o) v += t;
    }
    if (lane == 63) ls[w] = v;
    __syncthreads();
    int add = 0;
    #pragma unroll
    for (int i = 0; i < 4; i++) add += (i < w) ? ls[i] : 0;
    return v + add;
}

// ---------------- prep: bf16-transposed weights + zero HIST/MEANB -----------
__global__ __launch_bounds__(256) void k_prep(const float* __restrict__ Wl1,
                                              const float* __restrict__ Wr1,
                                              const float* __restrict__ Wl2,
                                              const float* __restrict__ Wr2,
                                              unsigned short* __restrict__ WT,
                                              unsigned short* __restrict__ WT2,
                                              int* __restrict__ hist,
                                              float* __restrict__ meanbuf) {
    int idx = blockIdx.x * 256 + threadIdx.x;     // 160 blocks -> 40960
    if (idx == 0) meanbuf[0] = 0.f;
    for (int i = idx; i < NC * NNODES; i += 160 * 256) hist[i] = 0;  // coalesced zero
    if (idx < 32768) {
        int mat = idx >> 14, rem = idx & 16383;
        int k = rem >> 7, n = rem & 127;
        float v = mat ? Wr1[k * 128 + n] : Wl1[k * 128 + n];
        WT[(size_t)(mat * 128 + n) * WTS + k] = bf16r(v);
    } else {
        int i2 = idx - 32768;                      // 8192 elements
        int mat = i2 >> 12, rem = i2 & 4095;
        int k = rem >> 5, n = rem & 31;
        float v = mat ? Wr2[k * 32 + n] : Wl2[k * 32 + n];
        WT2[(size_t)(mat * 32 + n) * WTS + k] = bf16r(v);
    }
}

// ---------------- fused & INTERLEAVED: conv1 MFMA GEMM + histogram ----------
// blockIdx%3==0 -> GEMM block (ordinal blockIdx/3); else histogram block.
// Hist: atomicAdd return value saved as EOFF[e] -> k_fill needs no atomics.
__global__ __launch_bounds__(256) void k_xf_eh(
    const float* __restrict__ x,
    const float* __restrict__ bl, const float* __restrict__ br,
    const unsigned short* __restrict__ WT,
    unsigned* __restrict__ xlb, float* __restrict__ xr,
    const int* __restrict__ ei, const float* __restrict__ ea,
    int* __restrict__ hist, int* __restrict__ eoff,
    float* __restrict__ meanbuf) {
    __shared__ short xs_s[64 * XSS];              // rows 0-31 hi, 32-63 lo
    int bi = blockIdx.x;
    if (bi % 3 != 0) {
        // ---- histogram (replicated) + edge_attr mean + slot offset ----
        float* ls = (float*)xs_s;
        int hb = bi - bi / 3 - 1;                 // hist ordinal 0..3125
        if (hb >= EHB) return;
        int e = hb * 256 + threadIdx.x;
        int c = hb & (NC - 1);                    // wave-uniform copy index
        float v = 0.f;
        if (e < NEDGES) {
            eoff[e] = atomicAdd(&hist[c * NNODES + ei[NEDGES + e]], 1);
            v = ea[e];
        }
        #pragma unroll
        for (int o = 32; o > 0; o >>= 1) v += __shfl_down(v, o, 64);
        if ((threadIdx.x & 63) == 0) ls[threadIdx.x >> 6] = v;
        __syncthreads();
        if (threadIdx.x == 0) atomicAdd(meanbuf, ls[0] + ls[1] + ls[2] + ls[3]);
        return;
    }
    int n0g = (bi / 3) * 32;
    // ---- stage x tile: 32 nodes x 128 k, bf16 hi + lo ----
    {
        int nd = threadIdx.x >> 3, kc = (threadIdx.x & 7) * 16;
        bool valid = (n0g + nd) < NNODES;
        float xv[16];
        #pragma unroll
        for (int i = 0; i < 4; i++) {
            float4 t = valid ? ((const float4*)(x + (size_t)(n0g + nd) * IN_CH + kc))[i]
                             : make_float4(0.f, 0.f, 0.f, 0.f);
            xv[4 * i] = t.x; xv[4 * i + 1] = t.y; xv[4 * i + 2] = t.z; xv[4 * i + 3] = t.w;
        }
        unsigned hi[8], lo[8];
        #pragma unroll
        for (int i = 0; i < 8; i++) {
            unsigned short h0 = bf16r(xv[2 * i]), h1 = bf16r(xv[2 * i + 1]);
            float l0 = xv[2 * i]     - __uint_as_float(((unsigned)h0) << 16);
            float l1 = xv[2 * i + 1] - __uint_as_float(((unsigned)h1) << 16);
            hi[i] = (unsigned)h0 | ((unsigned)h1 << 16);
            lo[i] = bf16pair(l0, l1);
        }
        uint4* ph = (uint4*)&xs_s[nd * XSS + kc];
        ph[0] = make_uint4(hi[0], hi[1], hi[2], hi[3]);
        ph[1] = make_uint4(hi[4], hi[5], hi[6], hi[7]);
        uint4* pl = (uint4*)&xs_s[(nd + 32) * XSS + kc];
        pl[0] = make_uint4(lo[0], lo[1], lo[2], lo[3]);
        pl[1] = make_uint4(lo[4], lo[5], lo[6], lo[7]);
    }
    __syncthreads();
    int lane = threadIdx.x & 63;
    int lm = lane & 15, q = lane >> 4;
    int w = threadIdx.x >> 6;
    int n0 = w * 64;                               // this wave's 64 output cols
    f32x4 acc[2][4];
    #pragma unroll
    for (int mt = 0; mt < 2; mt++)
        #pragma unroll
        for (int nt = 0; nt < 4; nt++) acc[mt][nt] = (f32x4)0.f;

    #pragma unroll
    for (int ks = 0; ks < 4; ks++) {
        int k0 = ks * 32 + q * 8;
        short8 ah0 = *(const short8*)&xs_s[(lm)      * XSS + k0];
        short8 ah1 = *(const short8*)&xs_s[(16 + lm) * XSS + k0];
        short8 al0 = *(const short8*)&xs_s[(32 + lm) * XSS + k0];
        short8 al1 = *(const short8*)&xs_s[(48 + lm) * XSS + k0];
        #pragma unroll
        for (int nt = 0; nt < 4; nt++) {
            short8 bfr = *(const short8*)(WT + (size_t)(n0 + nt * 16 + lm) * WTS + k0);
            acc[0][nt] = __builtin_amdgcn_mfma_f32_16x16x32_bf16(al0, bfr, acc[0][nt], 0, 0, 0);
            acc[0][nt] = __builtin_amdgcn_mfma_f32_16x16x32_bf16(ah0, bfr, acc[0][nt], 0, 0, 0);
            acc[1][nt] = __builtin_amdgcn_mfma_f32_16x16x32_bf16(al1, bfr, acc[1][nt], 0, 0, 0);
            acc[1][nt] = __builtin_amdgcn_mfma_f32_16x16x32_bf16(ah1, bfr, acc[1][nt], 0, 0, 0);
        }
    }
    // ---- epilogue: D row=(q*4+reg), col=lm ----
    if (w < 2) {
        #pragma unroll
        for (int nt = 0; nt < 4; nt++) {
            int ch = n0 + nt * 16 + lm;
            float bv = bl[ch];
            #pragma unroll
            for (int mt = 0; mt < 2; mt++)
                #pragma unroll
                for (int r = 0; r < 4; r++) {
                    int node = n0g + mt * 16 + q * 4 + r;
                    float val = acc[mt][nt][r] + bv;
                    float pv = __shfl_xor(val, 1);
                    if ((lm & 1) == 0 && node < NNODES)
                        xlb[(size_t)node * 64 + (ch >> 1)] = bf16pair(val, pv);
                }
        }
    } else {
        #pragma unroll
        for (int nt = 0; nt < 4; nt++) {
            int ch = n0 - 128 + nt * 16 + lm;
            float bv = br[ch];
            #pragma unroll
            for (int mt = 0; mt < 2; mt++)
                #pragma unroll
                for (int r = 0; r < 4; r++) {
                    int node = n0g + mt * 16 + q * 4 + r;
                    if (node < NNODES)
                        xr[(size_t)node * C1 + ch] = acc[mt][nt][r] + bv;
                }
        }
    }
}

// ---------------- reduce 16 histogram copies -> DEG + per-block sums --------
__global__ __launch_bounds__(256) void k_red(int* __restrict__ hist,
                                             int* __restrict__ deg,
                                             int* __restrict__ bsum) {
    __shared__ int ls[4];
    int d = blockIdx.x * 256 + threadIdx.x;
    int s = 0;
    if (d < NNODES) {
        #pragma unroll
        for (int c = 0; c < NC; c++) {
            int v = hist[c * NNODES + d];
            hist[c * NNODES + d] = s;
            s += v;
        }
        deg[d] = s;
    }
    int v = (d < NNODES) ? s + 1 : 0;              // +1 = self loop
    #pragma unroll
    for (int o = 32; o > 0; o >>= 1) v += __shfl_down(v, o, 64);
    if ((threadIdx.x & 63) == 0) ls[threadIdx.x >> 6] = v;
    __syncthreads();
    if (threadIdx.x == 0) bsum[blockIdx.x] = ls[0] + ls[1] + ls[2] + ls[3];
}

// ---------------- rowptr: inline bsum scan + in-block exclusive scan --------
// (k_bscan folded in: every block redundantly scans the 196 block sums)
__global__ __launch_bounds__(256) void k_rowp(const int* __restrict__ deg,
                                              const int* __restrict__ bsum,
                                              int* __restrict__ rowptr) {
    __shared__ int ls[4];
    int t = threadIdx.x;
    // scan bsum (196 ints) to get this block's base
    int bv = (t < SCB) ? bsum[t] : 0;
    int bincl = block_iscan(bv, ls);
    __shared__ int boffs[256];
    boffs[t] = bincl - bv;
    __syncthreads();
    int base = boffs[blockIdx.x];
    __syncthreads();                               // ls reuse barrier
    int d = blockIdx.x * 256 + t;
    int v = (d < NNODES) ? deg[d] + 1 : 0;
    int incl = block_iscan(v, ls);
    if (d < NNODES) rowptr[d] = base + incl - v;
    if (d == NNODES - 1) rowptr[NNODES] = base + incl;
}

// ---------------- CSR fill: ATOMIC-FREE. pos = rowptr + prefix + eoff -------
__global__ __launch_bounds__(256) void k_fill(const int* __restrict__ ei,
                                              const float* __restrict__ ea,
                                              const int* __restrict__ rowptr,
                                              const float* __restrict__ meanbuf,
                                              const int* __restrict__ hist,
                                              const int* __restrict__ eoff,
                                              unsigned* __restrict__ cpack) {
    int e = blockIdx.x * 256 + threadIdx.x;
    if (e < NEDGES) {
        int d = ei[NEDGES + e];
        int c = (e >> 8) & (NC - 1);
        int pos = rowptr[d] + 1 + hist[c * NNODES + d] + eoff[e];
        cpack[pos] = ((unsigned)bf16r(ea[e]) << 16) | (unsigned)ei[e];
    } else if (e < NEDGES + NNODES) {
        int i = e - NEDGES;
        cpack[rowptr[i]] = ((unsigned)bf16r(meanbuf[0] * (1.0f / NEDGES)) << 16) | (unsigned)i;
    } else if (e < NEDGES + NNODES + 64) {
        cpack[ETOT + e - NEDGES - NNODES] = 0u;
    }
}

// ---------------- conv1 fused edge phase: one wave/node ---------------------
// lane: q=lane&15 owns channels {8q..8q+7} (one uint4 bf16 gather); slot
// s=lane>>4 -> 4 edges in flight; TWO-DEEP software pipeline -> 8 rows
// outstanding per wave. Head logit = 4-lane xor reduce.
__global__ __launch_bounds__(256) void k_edge1(
    const unsigned* __restrict__ xlb, const float* __restrict__ xr,
    const int* __restrict__ rowptr, const unsigned* __restrict__ cpack,
    const float* __restrict__ We, const float* __restrict__ att,
    float* __restrict__ out1) {
    int node = blockIdx.x * 4 + (threadIdx.x >> 6);
    if (node >= NNODES) return;
    int lane = threadIdx.x & 63;
    int q = lane & 15, s = lane >> 4;
    int r0 = rowptr[node], r1 = rowptr[node + 1];
    float4 xr0 = ((const float4*)xr)[(size_t)node * 32 + 2 * q];
    float4 xr1 = ((const float4*)xr)[(size_t)node * 32 + 2 * q + 1];
    float4 we0 = ((const float4*)We)[2 * q],  we1 = ((const float4*)We)[2 * q + 1];
    float4 at0 = ((const float4*)att)[2 * q], at1 = ((const float4*)att)[2 * q + 1];
    const uint4* xlv = (const uint4*)xlb;      // row = 16 uint4 (128 ch)

    float den = 0.f;
    float a0 = 0.f, a1 = 0.f, a2 = 0.f, a3 = 0.f;
    float a4 = 0.f, a5 = 0.f, a6 = 0.f, a7 = 0.f;
    int nit = (r1 - r0 + 3) >> 2;
    int k = r0 + s;
    unsigned sc0 = cpack[k];                   // pipeline stage 0 (padded: safe)
    uint4 xv0 = xlv[(size_t)(sc0 & 0xffffu) * 16 + q];
    unsigned sc1 = cpack[k + 4];               // pipeline stage 1
    uint4 xv1 = xlv[(size_t)(sc1 & 0xffffu) * 16 + q];
    for (int it = 0; it < nit; it++) {
        unsigned scn = cpack[k + 8];           // prefetch 2 iterations ahead
        uint4 xvn = xlv[(size_t)(scn & 0xffffu) * 16 + q];
        bool ok = k < r1;
        float av = __uint_as_float(sc0 & 0xffff0000u);  // bf16 attr
        float x0 = blo(xv0.x), x1 = bhi(xv0.x), x2 = blo(xv0.y), x3 = bhi(xv0.y);
        float x4 = blo(xv0.z), x5 = bhi(xv0.z), x6 = blo(xv0.w), x7 = bhi(xv0.w);
        float v0 = x0 + xr0.x + av * we0.x;  v0 = v0 > 0.f ? v0 : NEG * v0;
        float v1 = x1 + xr0.y + av * we0.y;  v1 = v1 > 0.f ? v1 : NEG * v1;
        float v2 = x2 + xr0.z + av * we0.z;  v2 = v2 > 0.f ? v2 : NEG * v2;
        float v3 = x3 + xr0.w + av * we0.w;  v3 = v3 > 0.f ? v3 : NEG * v3;
        float v4 = x4 + xr1.x + av * we1.x;  v4 = v4 > 0.f ? v4 : NEG * v4;
        float v5 = x5 + xr1.y + av * we1.y;  v5 = v5 > 0.f ? v5 : NEG * v5;
        float v6 = x6 + xr1.z + av * we1.z;  v6 = v6 > 0.f ? v6 : NEG * v6;
        float v7 = x7 + xr1.w + av * we1.w;  v7 = v7 > 0.f ? v7 : NEG * v7;
        float t = v0 * at0.x + v1 * at0.y + v2 * at0.z + v3 * at0.w
                + v4 * at1.x + v5 * at1.y + v6 * at1.z + v7 * at1.w;
        t += __shfl_xor(t, 1);
        t += __shfl_xor(t, 2);                 // 4-lane group = this lane's head
        float e = ok ? __expf(t) : 0.f;
        den += e;
        a0 = fmaf(e, x0, a0); a1 = fmaf(e, x1, a1);
        a2 = fmaf(e, x2, a2); a3 = fmaf(e, x3, a3);
        a4 = fmaf(e, x4, a4); a5 = fmaf(e, x5, a5);
        a6 = fmaf(e, x6, a6); a7 = fmaf(e, x7, a7);
        k += 4;
        sc0 = sc1; xv0 = xv1;
        sc1 = scn; xv1 = xvn;
    }
    // merge the 4 slots (lanes q, q+16, q+32, q+48 hold same channels/head)
    #pragma unroll
    for (int o = 16; o <= 32; o <<= 1) {
        den += __shfl_xor(den, o);
        a0 += __shfl_xor(a0, o); a1 += __shfl_xor(a1, o);
        a2 += __shfl_xor(a2, o); a3 += __shfl_xor(a3, o);
        a4 += __shfl_xor(a4, o); a5 += __shfl_xor(a5, o);
        a6 += __shfl_xor(a6, o); a7 += __shfl_xor(a7, o);
    }
    if (s == 0) {
        float rd = 1.f / den;
        ((float4*)out1)[(size_t)node * 32 + 2 * q] =
            make_float4(a0 * rd, a1 * rd, a2 * rd, a3 * rd);
        ((float4*)out1)[(size_t)node * 32 + 2 * q + 1] =
            make_float4(a4 * rd, a5 * rd, a6 * rd, a7 * rd);
    }
}

// ---------------- epi1 via MFMA: BN+ReLU staged, then h @ (Wl2|Wr2) ---------
__global__ __launch_bounds__(256) void k_epi(
    const float* __restrict__ out1, const float* __restrict__ bias1,
    const float* __restrict__ g1, const float* __restrict__ b1,
    const float* __restrict__ m1, const float* __restrict__ v1,
    const unsigned short* __restrict__ WT2,
    const float* __restrict__ bl2, const float* __restrict__ br2,
    unsigned* __restrict__ xlb2, float* __restrict__ xr2) {
    __shared__ short hs_s[64 * XSS];              // rows 0-31 hi, 32-63 lo
    __shared__ float A[128], B[128];
    int n0g = blockIdx.x * 32;
    if (threadIdx.x < 128) {
        int c = threadIdx.x;
        float sc = g1[c] * rsqrtf(v1[c] + BNEPS);
        A[c] = sc;
        B[c] = (bias1[c] - m1[c]) * sc + b1[c];
    }
    __syncthreads();
    {
        int nd = threadIdx.x >> 3, kc = (threadIdx.x & 7) * 16;
        bool valid = (n0g + nd) < NNODES;
        float xv[16];
        #pragma unroll
        for (int i = 0; i < 4; i++) {
            float4 t = valid ? ((const float4*)(out1 + (size_t)(n0g + nd) * C1 + kc))[i]
                             : make_float4(0.f, 0.f, 0.f, 0.f);
            xv[4 * i] = t.x; xv[4 * i + 1] = t.y; xv[4 * i + 2] = t.z; xv[4 * i + 3] = t.w;
        }
        #pragma unroll
        for (int j = 0; j < 16; j++)
            xv[j] = fmaxf(xv[j] * A[kc + j] + B[kc + j], 0.f);   // BN + ReLU
        unsigned hi[8], lo[8];
        #pragma unroll
        for (int i = 0; i < 8; i++) {
            unsigned short h0 = bf16r(xv[2 * i]), h1 = bf16r(xv[2 * i + 1]);
            float l0 = xv[2 * i]     - __uint_as_float(((unsigned)h0) << 16);
            float l1 = xv[2 * i + 1] - __uint_as_float(((unsigned)h1) << 16);
            hi[i] = (unsigned)h0 | ((unsigned)h1 << 16);
            lo[i] = bf16pair(l0, l1);
        }
        uint4* ph = (uint4*)&hs_s[nd * XSS + kc];
        ph[0] = make_uint4(hi[0], hi[1], hi[2], hi[3]);
        ph[1] = make_uint4(hi[4], hi[5], hi[6], hi[7]);
        uint4* pl = (uint4*)&hs_s[(nd + 32) * XSS + kc];
        pl[0] = make_uint4(lo[0], lo[1], lo[2], lo[3]);
        pl[1] = make_uint4(lo[4], lo[5], lo[6], lo[7]);
    }
    __syncthreads();
    int lane = threadIdx.x & 63;
    int lm = lane & 15, q = lane >> 4;
    int w = threadIdx.x >> 6;
    f32x4 acc[2];
    acc[0] = (f32x4)0.f; acc[1] = (f32x4)0.f;
    #pragma unroll
    for (int ks = 0; ks < 4; ks++) {
        int k0 = ks * 32 + q * 8;
        short8 ah0 = *(const short8*)&hs_s[(lm)      * XSS + k0];
        short8 ah1 = *(const short8*)&hs_s[(16 + lm) * XSS + k0];
        short8 al0 = *(const short8*)&hs_s[(32 + lm) * XSS + k0];
        short8 al1 = *(const short8*)&hs_s[(48 + lm) * XSS + k0];
        short8 bfr = *(const short8*)(WT2 + (size_t)(w * 16 + lm) * WTS + k0);
        acc[0] = __builtin_amdgcn_mfma_f32_16x16x32_bf16(al0, bfr, acc[0], 0, 0, 0);
        acc[0] = __builtin_amdgcn_mfma_f32_16x16x32_bf16(ah0, bfr, acc[0], 0, 0, 0);
        acc[1] = __builtin_amdgcn_mfma_f32_16x16x32_bf16(al1, bfr, acc[1], 0, 0, 0);
        acc[1] = __builtin_amdgcn_mfma_f32_16x16x32_bf16(ah1, bfr, acc[1], 0, 0, 0);
    }
    if (w < 2) {
        int ch = w * 16 + lm;                      // Wl2 col 0..31
        float bv = bl2[ch];
        #pragma unroll
        for (int mt = 0; mt < 2; mt++)
            #pragma unroll
            for (int r = 0; r < 4; r++) {
                int node = n0g + mt * 16 + q * 4 + r;
                float val = acc[mt][r] + bv;
                float pv = __shfl_xor(val, 1);
                if ((lm & 1) == 0 && node < NNODES)
                    xlb2[(size_t)node * 16 + (ch >> 1)] = bf16pair(val, pv);
            }
    } else {
        int ch = (w - 2) * 16 + lm;                // Wr2 col 0..31
        float bv = br2[ch];
        #pragma unroll
        for (int mt = 0; mt < 2; mt++)
            #pragma unroll
            for (int r = 0; r < 4; r++) {
                int node = n0g + mt * 16 + q * 4 + r;
                if (node < NNODES)
                    xr2[(size_t)node * HID + ch] = acc[mt][r] + bv;
            }
    }
}

// ---------------- conv2 fused edge phase + BN + classifier ------------------
// lane: q=lane&3 owns channels {8q..8q+7}; slot s=lane>>2 -> 16 edges in flight
__global__ __launch_bounds__(256) void k_edge2(
    const unsigned* __restrict__ xlb2, const float* __restrict__ xr2,
    const int* __restrict__ rowptr, const unsigned* __restrict__ cpack,
    const float* __restrict__ We2, const float* __restrict__ att2,
    const float* __restrict__ bias2,
    const float* __restrict__ g2, const float* __restrict__ b2,
    const float* __restrict__ m2, const float* __restrict__ v2,
    const float* __restrict__ W, const float* __restrict__ b,
    float* __restrict__ y) {
    int node = blockIdx.x * 4 + (threadIdx.x >> 6);
    if (node >= NNODES) return;
    int lane = threadIdx.x & 63;
    int q = lane & 3, s = lane >> 2;
    int r0 = rowptr[node], r1 = rowptr[node + 1];
    float4 xr0 = ((const float4*)xr2)[(size_t)node * 8 + 2 * q];
    float4 xr1 = ((const float4*)xr2)[(size_t)node * 8 + 2 * q + 1];
    float4 we0 = ((const float4*)We2)[2 * q],  we1 = ((const float4*)We2)[2 * q + 1];
    float4 at0 = ((const float4*)att2)[2 * q], at1 = ((const float4*)att2)[2 * q + 1];
    const uint4* xlv = (const uint4*)xlb2;     // row = 4 uint4 (32 ch)

    float den = 0.f;
    float a0 = 0.f, a1 = 0.f, a2 = 0.f, a3 = 0.f;
    float a4 = 0.f, a5 = 0.f, a6 = 0.f, a7 = 0.f;
    int nit = (r1 - r0 + 15) >> 4;
    int k = r0 + s;
    unsigned sc = cpack[k];
    uint4 xv = xlv[(size_t)(sc & 0xffffu) * 4 + q];
    for (int it = 0; it < nit; it++) {
        unsigned scn = cpack[k + 16];          // unconditional prefetch (padded)
        uint4 xvn = xlv[(size_t)(scn & 0xffffu) * 4 + q];
        bool ok = k < r1;
        float av = __uint_as_float(sc & 0xffff0000u);
        float x0 = blo(xv.x), x1 = bhi(xv.x), x2 = blo(xv.y), x3 = bhi(xv.y);
        float x4 = blo(xv.z), x5 = bhi(xv.z), x6 = blo(xv.w), x7 = bhi(xv.w);
        float v0 = x0 + xr0.x + av * we0.x;  v0 = v0 > 0.f ? v0 : NEG * v0;
        float v1 = x1 + xr0.y + av * we0.y;  v1 = v1 > 0.f ? v1 : NEG * v1;
        float v2 = x2 + xr0.z + av * we0.z;  v2 = v2 > 0.f ? v2 : NEG * v2;
        float v3 = x3 + xr0.w + av * we0.w;  v3 = v3 > 0.f ? v3 : NEG * v3;
        float v4 = x4 + xr1.x + av * we1.x;  v4 = v4 > 0.f ? v4 : NEG * v4;
        float v5 = x5 + xr1.y + av * we1.y;  v5 = v5 > 0.f ? v5 : NEG * v5;
        float v6 = x6 + xr1.z + av * we1.z;  v6 = v6 > 0.f ? v6 : NEG * v6;
        float v7 = x7 + xr1.w + av * we1.w;  v7 = v7 > 0.f ? v7 : NEG * v7;
        float t = v0 * at0.x + v1 * at0.y + v2 * at0.z + v3 * at0.w
                + v4 * at1.x + v5 * at1.y + v6 * at1.z + v7 * at1.w;
        t += __shfl_xor(t, 1);
        t += __shfl_xor(t, 2);                 // full 32-ch logit
        float e = ok ? __expf(t) : 0.f;
        den += e;
        a0 = fmaf(e, x0, a0); a1 = fmaf(e, x1, a1);
        a2 = fmaf(e, x2, a2); a3 = fmaf(e, x3, a3);
        a4 = fmaf(e, x4, a4); a5 = fmaf(e, x5, a5);
        a6 = fmaf(e, x6, a6); a7 = fmaf(e, x7, a7);
        k += 16; sc = scn; xv = xvn;
    }
    #pragma unroll
    for (int o = 4; o <= 32; o <<= 1) {
        den += __shfl_xor(den, o);
        a0 += __shfl_xor(a0, o); a1 += __shfl_xor(a1, o);
        a2 += __shfl_xor(a2, o); a3 += __shfl_xor(a3, o);
        a4 += __shfl_xor(a4, o); a5 += __shfl_xor(a5, o);
        a6 += __shfl_xor(a6, o); a7 += __shfl_xor(a7, o);
    }
    float rd = 1.f / den;
    float4 gv0 = ((const float4*)g2)[2 * q],    gv1 = ((const float4*)g2)[2 * q + 1];
    float4 bv0 = ((const float4*)b2)[2 * q],    bv1 = ((const float4*)b2)[2 * q + 1];
    float4 mv0 = ((const float4*)m2)[2 * q],    mv1 = ((const float4*)m2)[2 * q + 1];
    float4 vv0 = ((const float4*)v2)[2 * q],    vv1 = ((const float4*)v2)[2 * q + 1];
    float4 bi0 = ((const float4*)bias2)[2 * q], bi1 = ((const float4*)bias2)[2 * q + 1];
    float h0 = (a0 * rd + bi0.x - mv0.x) * (gv0.x * rsqrtf(vv0.x + BNEPS)) + bv0.x;
    float h1 = (a1 * rd + bi0.y - mv0.y) * (gv0.y * rsqrtf(vv0.y + BNEPS)) + bv0.y;
    float h2 = (a2 * rd + bi0.z - mv0.z) * (gv0.z * rsqrtf(vv0.z + BNEPS)) + bv0.z;
    float h3 = (a3 * rd + bi0.w - mv0.w) * (gv0.w * rsqrtf(vv0.w + BNEPS)) + bv0.w;
    float h4 = (a4 * rd + bi1.x - mv1.x) * (gv1.x * rsqrtf(vv1.x + BNEPS)) + bv1.x;
    float h5 = (a5 * rd + bi1.y - mv1.y) * (gv1.y * rsqrtf(vv1.y + BNEPS)) + bv1.y;
    float h6 = (a6 * rd + bi1.z - mv1.z) * (gv1.z * rsqrtf(vv1.z + BNEPS)) + bv1.z;
    float h7 = (a7 * rd + bi1.w - mv1.w) * (gv1.w * rsqrtf(vv1.w + BNEPS)) + bv1.w;
    h0 = fmaxf(h0, 0.f); h1 = fmaxf(h1, 0.f); h2 = fmaxf(h2, 0.f); h3 = fmaxf(h3, 0.f);
    h4 = fmaxf(h4, 0.f); h5 = fmaxf(h5, 0.f); h6 = fmaxf(h6, 0.f); h7 = fmaxf(h7, 0.f);
    float4 w0 = ((const float4*)W)[4 * q];
    float4 w1 = ((const float4*)W)[4 * q + 1];
    float4 w2 = ((const float4*)W)[4 * q + 2];
    float4 w3 = ((const float4*)W)[4 * q + 3];
    float t0 = h0 * w0.x + h1 * w0.z + h2 * w1.x + h3 * w1.z
             + h4 * w2.x + h5 * w2.z + h6 * w3.x + h7 * w3.z;
    float t1 = h0 * w0.y + h1 * w0.w + h2 * w1.y + h3 * w1.w
             + h4 * w2.y + h5 * w2.w + h6 * w3.y + h7 * w3.w;
    t0 += __shfl_xor(t0, 1); t0 += __shfl_xor(t0, 2);
    t1 += __shfl_xor(t1, 1); t1 += __shfl_xor(t1, 2);
    if (lane == 0) {
        y[(size_t)node * 2]     = t0 + b[0];
        y[(size_t)node * 2 + 1] = t1 + b[1];
    }
}

extern "C" void kernel_launch(void* const* d_in, const int* in_sizes, int n_in,
                              void* d_out, int out_size, void* d_ws, size_t ws_size,
                              hipStream_t stream) {
    const float* x       = (const float*)d_in[0];
    const int*   ei      = (const int*)d_in[1];
    const float* ea      = (const float*)d_in[2];
    const float* c1_Wl   = (const float*)d_in[3];
    const float* c1_bl   = (const float*)d_in[4];
    const float* c1_Wr   = (const float*)d_in[5];
    const float* c1_br   = (const float*)d_in[6];
    const float* c1_We   = (const float*)d_in[7];
    const float* c1_att  = (const float*)d_in[8];
    const float* c1_bias = (const float*)d_in[9];
    const float* bn1_g   = (const float*)d_in[10];
    const float* bn1_b   = (const float*)d_in[11];
    const float* bn1_m   = (const float*)d_in[12];
    const float* bn1_v   = (const float*)d_in[13];
    const float* c2_Wl   = (const float*)d_in[14];
    const float* c2_bl   = (const float*)d_in[15];
    const float* c2_Wr   = (const float*)d_in[16];
    const float* c2_br   = (const float*)d_in[17];
    const float* c2_We   = (const float*)d_in[18];
    const float* c2_att  = (const float*)d_in[19];
    const float* c2_bias = (const float*)d_in[20];
    const float* bn2_g   = (const float*)d_in[21];
    const float* bn2_b   = (const float*)d_in[22];
    const float* bn2_m   = (const float*)d_in[23];
    const float* bn2_v   = (const float*)d_in[24];
    const float* clf_W   = (const float*)d_in[25];
    const float* clf_b   = (const float*)d_in[26];

    float* ws = (float*)d_ws;
    size_t off = 0;
    unsigned* XLb  = (unsigned*)(ws + off); off += (size_t)NNODES * 64;  // bf16x2
    float*    XR1  = ws + off; off += (size_t)NNODES * C1;
    float*    OUT1 = ws + off; off += (size_t)NNODES * C1;
    unsigned* XLb2 = (unsigned*)(ws + off); off += (size_t)NNODES * 16;  // bf16x2
    float*    XR2  = ws + off; off += (size_t)NNODES * HID;
    unsigned* CPACK= (unsigned*)(ws + off); off += (size_t)ETOT + 64;    // 4B/edge
    unsigned short* WT  = (unsigned short*)(ws + off); off += 256 * WTS / 2;
    unsigned short* WT2 = (unsigned short*)(ws + off); off += 64 * WTS / 2;
    int*      EOFF = (int*)(ws + off); off += NEDGES;
    int*      ROWP = (int*)(ws + off); off += NNODES + 16;
    int*      DEG  = (int*)(ws + off); off += NNODES;
    int*      BSUM = (int*)(ws + off); off += 256;
    int*      HIST = (int*)(ws + off); off += (size_t)NC * NNODES;  // zeroed by k_prep
    float*    MEANB= ws + off; off += 64;
    if (ws_size < off * sizeof(float)) return;  // workspace too small: fail loudly

    k_prep  <<<160, 256, 0, stream>>>(c1_Wl, c1_Wr, c2_Wl, c2_Wr, WT, WT2, HIST, MEANB);
    k_xf_eh <<<3 * XFB2, 256, 0, stream>>>(x, c1_bl, c1_br, WT, XLb, XR1,
                                           ei, ea, HIST, EOFF, MEANB);
    k_red   <<<SCB, 256, 0, stream>>>(HIST, DEG, BSUM);
    k_rowp  <<<SCB, 256, 0, stream>>>(DEG, BSUM, ROWP);
    k_fill  <<<(NEDGES + NNODES + 64 + 255) / 256, 256, 0, stream>>>(ei, ea, ROWP, MEANB, HIST, EOFF, CPACK);
    k_edge1 <<<(NNODES + 3) / 4, 256, 0, stream>>>(XLb, XR1, ROWP, CPACK, c1_We, c1_att, OUT1);
    k_epi   <<<XFB2, 256, 0, stream>>>(OUT1, c1_bias, bn1_g, bn1_b, bn1_m, bn1_v,
                                       WT2, c2_bl, c2_br, XLb2, XR2);
    k_edge2 <<<(NNODES + 3) / 4, 256, 0, stream>>>(XLb2, XR2, ROWP, CPACK, c2_We, c2_att,
                                                   c2_bias, bn2_g, bn2_b, bn2_m, bn2_v,
                                                   clf_W, clf_b, (float*)d_out);
}